// Round 1
// baseline (6858.765 us; speedup 1.0000x reference)
//
#include <hip/hip_runtime.h>

#define TOK 49
#define CDIM 384
#define NH 12
#define HDIM 32
#define NWIN 64
#define BTOT 4096
#define OUTSZ (BTOT * TOK * CDIM)   // 77,070,336 floats per slab

// ---------------------------------------------------------------------------
// Kernel 1: QKV GEMM.  qkv[m, c] = sum_k x[m,k] * qkv_w[c,k] + qkv_b[c]
// M = 200704, K = 384, Ncols = 1152.  128x128 tile, 8x8 per thread, fp32.
// Columns [0,384) -> q slab, [384,768) -> k slab, [768,1152) -> v slab.
// ---------------------------------------------------------------------------
__launch_bounds__(256)
__global__ void k_qkv(const float* __restrict__ X, const float* __restrict__ W,
                      const float* __restrict__ Bq, float* __restrict__ qslab) {
  __shared__ float As[16][132];   // As[k][i]  (transposed store)
  __shared__ float Bs[16][132];   // Bs[k][c]
  const int tid = threadIdx.x;
  const int row0 = blockIdx.x * 128;
  const int col0 = blockIdx.y * 128;
  const int tx = tid & 15, ty = tid >> 4;

  float acc[8][8];
#pragma unroll
  for (int r = 0; r < 8; ++r)
#pragma unroll
    for (int c = 0; c < 8; ++c) acc[r][c] = 0.f;

  for (int kb = 0; kb < CDIM; kb += 16) {
#pragma unroll
    for (int l = 0; l < 8; ++l) {
      int idx = tid + l * 256;          // 0..2047
      int i = idx >> 4, j = idx & 15;
      As[j][i] = X[(size_t)(row0 + i) * CDIM + kb + j];
      Bs[j][i] = W[(size_t)(col0 + i) * CDIM + kb + j];
    }
    __syncthreads();
#pragma unroll
    for (int j = 0; j < 16; ++j) {
      float4 a0 = *(const float4*)&As[j][ty * 8];
      float4 a1 = *(const float4*)&As[j][ty * 8 + 4];
      float4 b0 = *(const float4*)&Bs[j][tx * 8];
      float4 b1 = *(const float4*)&Bs[j][tx * 8 + 4];
      float av[8] = {a0.x, a0.y, a0.z, a0.w, a1.x, a1.y, a1.z, a1.w};
      float bv[8] = {b0.x, b0.y, b0.z, b0.w, b1.x, b1.y, b1.z, b1.w};
#pragma unroll
      for (int r = 0; r < 8; ++r)
#pragma unroll
        for (int c = 0; c < 8; ++c)
          acc[r][c] = fmaf(av[r], bv[c], acc[r][c]);
    }
    __syncthreads();
  }

  const int slab  = col0 / CDIM;        // whole block lives in one slab (128 | 384)
  const int cbase = col0 % CDIM;
  float* dst = qslab + (size_t)slab * OUTSZ;
#pragma unroll
  for (int r = 0; r < 8; ++r) {
    int row = row0 + ty * 8 + r;
#pragma unroll
    for (int c = 0; c < 8; ++c) {
      int col = cbase + tx * 8 + c;
      dst[(size_t)row * CDIM + col] = acc[r][c] + Bq[col0 + tx * 8 + c];
    }
  }
}

// ---------------------------------------------------------------------------
// Kernel 2: per-window attention. One block per b (4096 blocks, 256 thr).
// S[h][n][m] in LDS (12*49*49 fp32 = 115 KB).  Phases:
//   A: S = scale*q.k^T + rpb bias        (per-head q/k tiles in LDS, pad 36)
//   B: proj_l head mix + window mask
//   C: row softmax
//   D: proj_w head mix
//   E: PV -> write attention output (pre-proj) into the `out` slab (staging)
// ---------------------------------------------------------------------------
__launch_bounds__(256)
__global__ void k_attn(const float* __restrict__ qslab, const float* __restrict__ kslab,
                       const float* __restrict__ vslab, const float* __restrict__ mask,
                       const float* __restrict__ rpb, const int* __restrict__ relidx,
                       const float* __restrict__ plw, const float* __restrict__ plb,
                       const float* __restrict__ pww, const float* __restrict__ pwb,
                       float* __restrict__ xout) {
  __shared__ float S[NH * TOK * TOK];   // 28812 floats = 115,248 B
  __shared__ float tq[TOK * 36];        // padded stride 36: float4-aligned, conflict-free
  __shared__ float tk[TOK * 36];
  const int b = blockIdx.x;
  const int tid = threadIdx.x;
  const float scale = 0.17677669529663687f;   // 32^-0.5
  const size_t base = (size_t)b * TOK * CDIM;

  // ---- Phase A: scores + relative-position bias
  for (int h = 0; h < NH; ++h) {
    for (int idx = tid; idx < TOK * HDIM; idx += 256) {
      int n = idx >> 5, d = idx & 31;
      tq[n * 36 + d] = qslab[base + n * CDIM + h * HDIM + d];
      tk[n * 36 + d] = kslab[base + n * CDIM + h * HDIM + d];
    }
    __syncthreads();
    for (int p = tid; p < TOK * TOK; p += 256) {
      int n = p / TOK, m = p - n * TOK;
      const float* qn = &tq[n * 36];
      const float* km = &tk[m * 36];
      float acc = 0.f;
#pragma unroll
      for (int j = 0; j < 8; ++j) {
        float4 a  = *(const float4*)&qn[4 * j];
        float4 bb = *(const float4*)&km[4 * j];
        acc += a.x * bb.x + a.y * bb.y + a.z * bb.z + a.w * bb.w;
      }
      S[h * (TOK * TOK) + p] = acc * scale + rpb[relidx[p] * NH + h];
    }
    __syncthreads();
  }

  // ---- Phase B: proj_l (head mixing) + window mask
  const int w = b & (NWIN - 1);
  for (int p = tid; p < TOK * TOK; p += 256) {
    float vh[NH], tmp[NH];
#pragma unroll
    for (int h = 0; h < NH; ++h) vh[h] = S[h * (TOK * TOK) + p];
    float mk = mask[w * (TOK * TOK) + p];
#pragma unroll
    for (int g = 0; g < NH; ++g) {
      float a = plb[g] + mk;
#pragma unroll
      for (int h = 0; h < NH; ++h) a = fmaf(plw[g * NH + h], vh[h], a);
      tmp[g] = a;
    }
#pragma unroll
    for (int g = 0; g < NH; ++g) S[g * (TOK * TOK) + p] = tmp[g];
  }
  __syncthreads();

  // ---- Phase C: softmax over m (588 rows of 49)
  for (int r = tid; r < NH * TOK; r += 256) {
    float* row = &S[r * TOK];
    float mx = -1e30f;
    for (int m = 0; m < TOK; ++m) mx = fmaxf(mx, row[m]);
    float sum = 0.f;
    for (int m = 0; m < TOK; ++m) { float e = __expf(row[m] - mx); row[m] = e; sum += e; }
    float inv = 1.f / sum;
    for (int m = 0; m < TOK; ++m) row[m] *= inv;
  }
  __syncthreads();

  // ---- Phase D: proj_w (head mixing after softmax)
  for (int p = tid; p < TOK * TOK; p += 256) {
    float vh[NH], tmp[NH];
#pragma unroll
    for (int h = 0; h < NH; ++h) vh[h] = S[h * (TOK * TOK) + p];
#pragma unroll
    for (int g = 0; g < NH; ++g) {
      float a = pwb[g];
#pragma unroll
      for (int h = 0; h < NH; ++h) a = fmaf(pww[g * NH + h], vh[h], a);
      tmp[g] = a;
    }
#pragma unroll
    for (int g = 0; g < NH; ++g) S[g * (TOK * TOK) + p] = tmp[g];
  }
  __syncthreads();

  // ---- Phase E: PV.  xout[b,n,g*32+d] = sum_m attn[g,n,m] * v[b,m,g*32+d]
  for (int g = 0; g < NH; ++g) {
    for (int idx = tid; idx < TOK * HDIM; idx += 256) {
      int n = idx >> 5, d = idx & 31;
      tq[n * 36 + d] = vslab[base + n * CDIM + g * HDIM + d];   // reuse tq as v tile
    }
    __syncthreads();
    for (int idx = tid; idx < TOK * HDIM; idx += 256) {
      int n = idx >> 5, d = idx & 31;
      const float* arow = &S[g * (TOK * TOK) + n * TOK];
      float acc = 0.f;
      for (int m = 0; m < TOK; ++m) acc = fmaf(arow[m], tq[m * 36 + d], acc);
      xout[base + n * CDIM + g * HDIM + d] = acc;
    }
    __syncthreads();
  }
}

// ---------------------------------------------------------------------------
// Kernel 3: in-place output projection.  Y[m,:] = Y[m,:] @ W^T + b.
// Each block owns 64 rows: stages the full 64x384 strip in LDS BEFORE any
// write, so in-place is race-free (out[m,c] depends only on row m).
// ---------------------------------------------------------------------------
__launch_bounds__(256)
__global__ void k_proj(float* Y, const float* __restrict__ W,
                       const float* __restrict__ Bv) {
  __shared__ float Xs[64 * 388];    // pad 388: float4-aligned rows
  __shared__ float Ws[16 * 68];
  const int tid = threadIdx.x;
  const int row0 = blockIdx.x * 64;

  // stage the row strip (float4; 96 float4 per row, no row crossing)
#pragma unroll
  for (int l = 0; l < 24; ++l) {
    int idx4 = tid + l * 256;
    int row = idx4 / 96;
    int k4  = idx4 - row * 96;
    float4 v = *(const float4*)&Y[(size_t)(row0 + row) * CDIM + k4 * 4];
    *(float4*)&Xs[row * 388 + k4 * 4] = v;
  }

  const int tx = tid & 15, ty = tid >> 4;
  for (int cc = 0; cc < 6; ++cc) {
    float acc[4][4];
#pragma unroll
    for (int r = 0; r < 4; ++r)
#pragma unroll
      for (int c = 0; c < 4; ++c) acc[r][c] = 0.f;

    for (int kb = 0; kb < 24; ++kb) {
      __syncthreads();                 // protects Ws overwrite (and Xs on 1st iter)
#pragma unroll
      for (int l = 0; l < 4; ++l) {
        int idx = tid + l * 256;       // 0..1023
        int c = idx >> 4, j = idx & 15;
        Ws[j * 68 + c] = W[(size_t)(cc * 64 + c) * CDIM + kb * 16 + j];
      }
      __syncthreads();
#pragma unroll
      for (int j = 0; j < 16; ++j) {
        float a[4];
#pragma unroll
        for (int r = 0; r < 4; ++r) a[r] = Xs[(ty * 4 + r) * 388 + kb * 16 + j];
        float4 b = *(const float4*)&Ws[j * 68 + tx * 4];
        float bv[4] = {b.x, b.y, b.z, b.w};
#pragma unroll
        for (int r = 0; r < 4; ++r)
#pragma unroll
          for (int c = 0; c < 4; ++c)
            acc[r][c] = fmaf(a[r], bv[c], acc[r][c]);
      }
    }
#pragma unroll
    for (int r = 0; r < 4; ++r) {
      int row = row0 + ty * 4 + r;
#pragma unroll
      for (int c = 0; c < 4; ++c) {
        int col = cc * 64 + tx * 4 + c;
        Y[(size_t)row * CDIM + col] = acc[r][c] + Bv[col];
      }
    }
  }
}

// ---------------------------------------------------------------------------
extern "C" void kernel_launch(void* const* d_in, const int* in_sizes, int n_in,
                              void* d_out, int out_size, void* d_ws, size_t ws_size,
                              hipStream_t stream) {
  const float* x      = (const float*)d_in[0];
  const float* mask   = (const float*)d_in[1];
  const float* qkv_w  = (const float*)d_in[2];
  const float* qkv_b  = (const float*)d_in[3];
  const float* rpb    = (const float*)d_in[4];
  const float* plw    = (const float*)d_in[5];
  const float* plb    = (const float*)d_in[6];
  const float* pww    = (const float*)d_in[7];
  const float* pwb    = (const float*)d_in[8];
  const float* projw  = (const float*)d_in[9];
  const float* projb  = (const float*)d_in[10];
  const int*   relidx = (const int*)d_in[11];

  float* out   = (float*)d_out;
  float* qslab = out + (size_t)OUTSZ;
  float* kslab = out + 2 * (size_t)OUTSZ;
  float* vslab = out + 3 * (size_t)OUTSZ;

  dim3 g1(BTOT * TOK / 128, (3 * CDIM) / 128);   // 1568 x 9
  k_qkv<<<g1, 256, 0, stream>>>(x, qkv_w, qkv_b, qslab);

  k_attn<<<BTOT, 256, 0, stream>>>(qslab, kslab, vslab, mask, rpb, relidx,
                                   plw, plb, pww, pwb, out);

  k_proj<<<BTOT * TOK / 64, 256, 0, stream>>>(out, projw, projb);
}

// Round 2
// 2459.981 us; speedup vs baseline: 2.7881x; 2.7881x over previous
//
#include <hip/hip_runtime.h>

#define TOK 49
#define CDIM 384
#define NH 12
#define HDIM 32
#define NWIN 64
#define BTOT 4096
#define OUTSZ (BTOT * TOK * CDIM)   // 77,070,336 floats per slab

typedef __attribute__((ext_vector_type(8))) short bf16x8;
typedef __attribute__((ext_vector_type(4))) float f32x4;
typedef unsigned int uint32;
typedef unsigned short ushort_t;

__device__ inline ushort_t f2bf(float f) {          // RNE fp32 -> bf16
  uint32 u = __float_as_uint(f);
  u += 0x7FFF + ((u >> 16) & 1);
  return (ushort_t)(u >> 16);
}

// ---------------------------------------------------------------------------
// fp32 -> bf16 bulk convert (8 elements / thread)
// ---------------------------------------------------------------------------
__global__ void k_cvt(const float* __restrict__ src, ushort_t* __restrict__ dst, int n8) {
  int i = blockIdx.x * 256 + threadIdx.x;
  if (i >= n8) return;
  const float4* s = (const float4*)(src + (size_t)i * 8);
  float4 a = s[0], b = s[1];
  uint4 o;
  o.x = (uint32)f2bf(a.x) | ((uint32)f2bf(a.y) << 16);
  o.y = (uint32)f2bf(a.z) | ((uint32)f2bf(a.w) << 16);
  o.z = (uint32)f2bf(b.x) | ((uint32)f2bf(b.y) << 16);
  o.w = (uint32)f2bf(b.z) | ((uint32)f2bf(b.w) << 16);
  *(uint4*)(dst + (size_t)i * 8) = o;
}

// ---------------------------------------------------------------------------
// Kernel 1: QKV GEMM, bf16 MFMA.  C[m,c] = sum_k X[m,k]*W[c,k] + b[c]
// 128x128 tile, BK=32, 4 waves (2x2), per-wave 64x64 = 4x4 MFMA tiles.
// ---------------------------------------------------------------------------
__launch_bounds__(256)
__global__ void k_qkv_mfma(const ushort_t* __restrict__ Xb, const ushort_t* __restrict__ Wb,
                           const float* __restrict__ Bq, float* __restrict__ qslab) {
  __shared__ ushort_t As[128 * 32];
  __shared__ ushort_t Bs[128 * 32];
  const int tid = threadIdx.x;
  const int l = tid & 63;
  const int wv = tid >> 6;
  const int wr = wv >> 1, wc = wv & 1;
  const int row0 = blockIdx.x * 128;
  const int col0 = blockIdx.y * 128;

  f32x4 acc[4][4];
#pragma unroll
  for (int i = 0; i < 4; ++i)
#pragma unroll
    for (int j = 0; j < 4; ++j)
#pragma unroll
      for (int e = 0; e < 4; ++e) acc[i][j][e] = 0.f;

  for (int kb = 0; kb < CDIM; kb += 32) {
#pragma unroll
    for (int i = 0; i < 2; ++i) {
      int cid = tid + i * 256;            // 0..511 chunk of 8 bf16
      int r = cid >> 2, c = cid & 3;
      uint4 v = *(const uint4*)&Xb[(size_t)(row0 + r) * CDIM + kb + c * 8];
      *(uint4*)&As[r * 32 + c * 8] = v;
      uint4 w = *(const uint4*)&Wb[(size_t)(col0 + r) * CDIM + kb + c * 8];
      *(uint4*)&Bs[r * 32 + c * 8] = w;
    }
    __syncthreads();
    bf16x8 af[4], bfr[4];
#pragma unroll
    for (int mt = 0; mt < 4; ++mt)
      af[mt] = *(const bf16x8*)&As[(wr * 64 + mt * 16 + (l & 15)) * 32 + (l >> 4) * 8];
#pragma unroll
    for (int nt = 0; nt < 4; ++nt)
      bfr[nt] = *(const bf16x8*)&Bs[(wc * 64 + nt * 16 + (l & 15)) * 32 + (l >> 4) * 8];
#pragma unroll
    for (int mt = 0; mt < 4; ++mt)
#pragma unroll
      for (int nt = 0; nt < 4; ++nt)
        acc[mt][nt] = __builtin_amdgcn_mfma_f32_16x16x32_bf16(af[mt], bfr[nt], acc[mt][nt], 0, 0, 0);
    __syncthreads();
  }

  const int by = blockIdx.y;
  const int slab = by / 3;                      // 0=q 1=k 2=v (128 | 384)
  const int cslab0 = col0 - slab * CDIM;
  float* dst = qslab + (size_t)slab * OUTSZ;
#pragma unroll
  for (int nt = 0; nt < 4; ++nt) {
    int colg = col0 + wc * 64 + nt * 16 + (l & 15);
    int colo = cslab0 + wc * 64 + nt * 16 + (l & 15);
    float bv = Bq[colg];
#pragma unroll
    for (int mt = 0; mt < 4; ++mt) {
      int rbase = row0 + wr * 64 + mt * 16 + (l >> 4) * 4;
#pragma unroll
      for (int j = 0; j < 4; ++j)
        dst[(size_t)(rbase + j) * CDIM + colo] = acc[mt][nt][j] + bv;
    }
  }
}

// ---------------------------------------------------------------------------
// Kernel 2: per-window attention. 1024 threads (16 waves) per block now.
// ---------------------------------------------------------------------------
__launch_bounds__(1024)
__global__ void k_attn(const float* __restrict__ qslab, const float* __restrict__ kslab,
                       const float* __restrict__ vslab, const float* __restrict__ mask,
                       const float* __restrict__ rpb, const int* __restrict__ relidx,
                       const float* __restrict__ plw, const float* __restrict__ plb,
                       const float* __restrict__ pww, const float* __restrict__ pwb,
                       float* __restrict__ xout) {
  __shared__ float S[NH * TOK * TOK];   // 115 KB
  __shared__ float tq[TOK * 36];
  __shared__ float tk[TOK * 36];
  const int b = blockIdx.x;
  const int tid = threadIdx.x;
  const float scale = 0.17677669529663687f;
  const size_t base = (size_t)b * TOK * CDIM;

  // ---- Phase A: scores + relative-position bias
  for (int h = 0; h < NH; ++h) {
    for (int idx = tid; idx < TOK * HDIM; idx += 1024) {
      int n = idx >> 5, d = idx & 31;
      tq[n * 36 + d] = qslab[base + n * CDIM + h * HDIM + d];
      tk[n * 36 + d] = kslab[base + n * CDIM + h * HDIM + d];
    }
    __syncthreads();
    for (int p = tid; p < TOK * TOK; p += 1024) {
      int n = p / TOK, m = p - n * TOK;
      const float* qn = &tq[n * 36];
      const float* km = &tk[m * 36];
      float acc = 0.f;
#pragma unroll
      for (int j = 0; j < 8; ++j) {
        float4 a  = *(const float4*)&qn[4 * j];
        float4 bb = *(const float4*)&km[4 * j];
        acc += a.x * bb.x + a.y * bb.y + a.z * bb.z + a.w * bb.w;
      }
      S[h * (TOK * TOK) + p] = acc * scale + rpb[relidx[p] * NH + h];
    }
    __syncthreads();
  }

  // ---- Phase B: proj_l (head mixing) + window mask
  const int w = b & (NWIN - 1);
  for (int p = tid; p < TOK * TOK; p += 1024) {
    float vh[NH], tmp[NH];
#pragma unroll
    for (int h = 0; h < NH; ++h) vh[h] = S[h * (TOK * TOK) + p];
    float mk = mask[w * (TOK * TOK) + p];
#pragma unroll
    for (int g = 0; g < NH; ++g) {
      float a = plb[g] + mk;
#pragma unroll
      for (int h = 0; h < NH; ++h) a = fmaf(plw[g * NH + h], vh[h], a);
      tmp[g] = a;
    }
#pragma unroll
    for (int g = 0; g < NH; ++g) S[g * (TOK * TOK) + p] = tmp[g];
  }
  __syncthreads();

  // ---- Phase C: softmax over m
  for (int r = tid; r < NH * TOK; r += 1024) {
    float* row = &S[r * TOK];
    float mx = -1e30f;
    for (int m = 0; m < TOK; ++m) mx = fmaxf(mx, row[m]);
    float sum = 0.f;
    for (int m = 0; m < TOK; ++m) { float e = __expf(row[m] - mx); row[m] = e; sum += e; }
    float inv = 1.f / sum;
    for (int m = 0; m < TOK; ++m) row[m] *= inv;
  }
  __syncthreads();

  // ---- Phase D: proj_w
  for (int p = tid; p < TOK * TOK; p += 1024) {
    float vh[NH], tmp[NH];
#pragma unroll
    for (int h = 0; h < NH; ++h) vh[h] = S[h * (TOK * TOK) + p];
#pragma unroll
    for (int g = 0; g < NH; ++g) {
      float a = pwb[g];
#pragma unroll
      for (int h = 0; h < NH; ++h) a = fmaf(pww[g * NH + h], vh[h], a);
      tmp[g] = a;
    }
#pragma unroll
    for (int g = 0; g < NH; ++g) S[g * (TOK * TOK) + p] = tmp[g];
  }
  __syncthreads();

  // ---- Phase E: PV
  for (int g = 0; g < NH; ++g) {
    for (int idx = tid; idx < TOK * HDIM; idx += 1024) {
      int n = idx >> 5, d = idx & 31;
      tq[n * 36 + d] = vslab[base + n * CDIM + g * HDIM + d];
    }
    __syncthreads();
    for (int idx = tid; idx < TOK * HDIM; idx += 1024) {
      int n = idx >> 5, d = idx & 31;
      const float* arow = &S[g * (TOK * TOK) + n * TOK];
      float acc = 0.f;
      for (int m = 0; m < TOK; ++m) acc = fmaf(arow[m], tq[m * 36 + d], acc);
      xout[base + n * CDIM + g * HDIM + d] = acc;
    }
    __syncthreads();
  }
}

// ---------------------------------------------------------------------------
// Kernel 3: output projection, bf16 MFMA, in-place.
// Block = 128-row strip x all 384 cols; strip staged (fp32->bf16) to LDS once
// BEFORE any write -> in-place is race-free. 8 waves (2x4), wave = 64x96.
// ---------------------------------------------------------------------------
__launch_bounds__(512)
__global__ void k_proj_mfma(float* __restrict__ Y, const float* __restrict__ W,
                            const float* __restrict__ Bv) {
  __shared__ ushort_t Asb[128 * 392];   // 100,352 B (stride 392 bf16)
  __shared__ ushort_t Bsb[384 * 40];    // 30,720 B  (stride 40 bf16)
  const int tid = threadIdx.x;
  const int l = tid & 63;
  const int wv = tid >> 6;              // 0..7
  const int wr = wv >> 2, wc = wv & 3;
  const int row0 = blockIdx.x * 128;

  // stage the whole 128x384 strip once, fp32 -> bf16
#pragma unroll
  for (int i = 0; i < 12; ++i) {
    int cid = tid + i * 512;            // 0..6143 chunk of 8
    int r = cid / 48, c8 = cid % 48;
    const float4* s = (const float4*)&Y[(size_t)(row0 + r) * CDIM + c8 * 8];
    float4 a = s[0], b = s[1];
    uint4 o;
    o.x = (uint32)f2bf(a.x) | ((uint32)f2bf(a.y) << 16);
    o.y = (uint32)f2bf(a.z) | ((uint32)f2bf(a.w) << 16);
    o.z = (uint32)f2bf(b.x) | ((uint32)f2bf(b.y) << 16);
    o.w = (uint32)f2bf(b.z) | ((uint32)f2bf(b.w) << 16);
    *(uint4*)&Asb[r * 392 + c8 * 8] = o;
  }

  f32x4 acc[4][6];
#pragma unroll
  for (int i = 0; i < 4; ++i)
#pragma unroll
    for (int j = 0; j < 6; ++j)
#pragma unroll
      for (int e = 0; e < 4; ++e) acc[i][j][e] = 0.f;

  for (int kb = 0; kb < CDIM; kb += 32) {
    __syncthreads();                    // A ready (1st iter) / Bsb consumed (later)
#pragma unroll
    for (int i = 0; i < 3; ++i) {
      int cid = tid + i * 512;          // 0..1535
      int col = cid >> 2, k8 = cid & 3;
      const float4* s = (const float4*)&W[(size_t)col * CDIM + kb + k8 * 8];
      float4 a = s[0], b = s[1];
      uint4 o;
      o.x = (uint32)f2bf(a.x) | ((uint32)f2bf(a.y) << 16);
      o.y = (uint32)f2bf(a.z) | ((uint32)f2bf(a.w) << 16);
      o.z = (uint32)f2bf(b.x) | ((uint32)f2bf(b.y) << 16);
      o.w = (uint32)f2bf(b.z) | ((uint32)f2bf(b.w) << 16);
      *(uint4*)&Bsb[col * 40 + k8 * 8] = o;
    }
    __syncthreads();
    bf16x8 af[4], bfr[6];
#pragma unroll
    for (int mt = 0; mt < 4; ++mt)
      af[mt] = *(const bf16x8*)&Asb[(wr * 64 + mt * 16 + (l & 15)) * 392 + kb + (l >> 4) * 8];
#pragma unroll
    for (int nt = 0; nt < 6; ++nt)
      bfr[nt] = *(const bf16x8*)&Bsb[(wc * 96 + nt * 16 + (l & 15)) * 40 + (l >> 4) * 8];
#pragma unroll
    for (int mt = 0; mt < 4; ++mt)
#pragma unroll
      for (int nt = 0; nt < 6; ++nt)
        acc[mt][nt] = __builtin_amdgcn_mfma_f32_16x16x32_bf16(af[mt], bfr[nt], acc[mt][nt], 0, 0, 0);
  }

#pragma unroll
  for (int nt = 0; nt < 6; ++nt) {
    int col = wc * 96 + nt * 16 + (l & 15);
    float bv = Bv[col];
#pragma unroll
    for (int mt = 0; mt < 4; ++mt) {
      int rbase = row0 + wr * 64 + mt * 16 + (l >> 4) * 4;
#pragma unroll
      for (int j = 0; j < 4; ++j)
        Y[(size_t)(rbase + j) * CDIM + col] = acc[mt][nt][j] + bv;
    }
  }
}

// ---------------------------------------------------------------------------
extern "C" void kernel_launch(void* const* d_in, const int* in_sizes, int n_in,
                              void* d_out, int out_size, void* d_ws, size_t ws_size,
                              hipStream_t stream) {
  const float* x      = (const float*)d_in[0];
  const float* mask   = (const float*)d_in[1];
  const float* qkv_w  = (const float*)d_in[2];
  const float* qkv_b  = (const float*)d_in[3];
  const float* rpb    = (const float*)d_in[4];
  const float* plw    = (const float*)d_in[5];
  const float* plb    = (const float*)d_in[6];
  const float* pww    = (const float*)d_in[7];
  const float* pwb    = (const float*)d_in[8];
  const float* projw  = (const float*)d_in[9];
  const float* projb  = (const float*)d_in[10];
  const int*   relidx = (const int*)d_in[11];

  float* out   = (float*)d_out;
  float* qslab = out + (size_t)OUTSZ;
  float* kslab = out + 2 * (size_t)OUTSZ;
  float* vslab = out + 3 * (size_t)OUTSZ;

  // bf16 scratch inside the (not-yet-needed) `out` slab:
  //   X-bf16 at float-offset 0 (77,070,336 ushorts = 38.5M floats)
  //   W-bf16 at float-offset 70,000,000 (442,368 ushorts)
  ushort_t* Xb = (ushort_t*)out;
  ushort_t* Wb = (ushort_t*)(out + 70000000);

  k_cvt<<<(OUTSZ / 8 + 255) / 256, 256, 0, stream>>>(x, Xb, OUTSZ / 8);
  k_cvt<<<(3 * CDIM * CDIM / 8 + 255) / 256, 256, 0, stream>>>(qkv_w, Wb, 3 * CDIM * CDIM / 8);

  dim3 g1(BTOT * TOK / 128, (3 * CDIM) / 128);   // 1568 x 9
  k_qkv_mfma<<<g1, 256, 0, stream>>>(Xb, Wb, qkv_b, qslab);

  k_attn<<<BTOT, 1024, 0, stream>>>(qslab, kslab, vslab, mask, rpb, relidx,
                                    plw, plb, pww, pwb, out);

  k_proj_mfma<<<BTOT * TOK / 128, 512, 0, stream>>>(out, projw, projb);
}

// Round 3
// 1934.762 us; speedup vs baseline: 3.5450x; 1.2715x over previous
//
#include <hip/hip_runtime.h>
#include <hip/hip_bf16.h>

#define TOK 49
#define CDIM 384
#define NH 12
#define HDIM 32
#define NWIN 64
#define BTOT 4096
#define OUTSZ (BTOT * TOK * CDIM)   // 77,070,336 floats per slab

typedef __attribute__((ext_vector_type(8))) short bf16x8;
typedef __attribute__((ext_vector_type(4))) float f32x4;
typedef unsigned int uint32;
typedef unsigned short ushort_t;

__device__ inline ushort_t f2bf(float f) {          // RNE fp32 -> bf16
  uint32 u = __float_as_uint(f);
  u += 0x7FFF + ((u >> 16) & 1);
  return (ushort_t)(u >> 16);
}
__device__ inline float bf2f(uint32 u) { return __uint_as_float((u & 0xffffu) << 16); }

__device__ inline bf16x8 pack8(float4 a, float4 b) {
  union { __hip_bfloat162 h[4]; bf16x8 v; } u;
  u.h[0] = __float22bfloat162_rn(float2{a.x, a.y});
  u.h[1] = __float22bfloat162_rn(float2{a.z, a.w});
  u.h[2] = __float22bfloat162_rn(float2{b.x, b.y});
  u.h[3] = __float22bfloat162_rn(float2{b.z, b.w});
  return u.v;
}

// ---------------------------------------------------------------------------
// fp32 -> bf16 bulk convert
// ---------------------------------------------------------------------------
__global__ void k_cvt(const float* __restrict__ src, ushort_t* __restrict__ dst, int n8) {
  int i = blockIdx.x * 256 + threadIdx.x;
  if (i >= n8) return;
  const float4* s = (const float4*)(src + (size_t)i * 8);
  float4 a = s[0], b = s[1];
  uint4 o;
  o.x = (uint32)f2bf(a.x) | ((uint32)f2bf(a.y) << 16);
  o.y = (uint32)f2bf(a.z) | ((uint32)f2bf(a.w) << 16);
  o.z = (uint32)f2bf(b.x) | ((uint32)f2bf(b.y) << 16);
  o.w = (uint32)f2bf(b.z) | ((uint32)f2bf(b.w) << 16);
  *(uint4*)(dst + (size_t)i * 8) = o;
}

// ---------------------------------------------------------------------------
// Kernel 1: QKV GEMM, bf16 MFMA (unchanged from round 2; absmax-verified).
// ---------------------------------------------------------------------------
__launch_bounds__(256)
__global__ void k_qkv_mfma(const ushort_t* __restrict__ Xb, const ushort_t* __restrict__ Wb,
                           const float* __restrict__ Bq, float* __restrict__ qslab) {
  __shared__ ushort_t As[128 * 32];
  __shared__ ushort_t Bs[128 * 32];
  const int tid = threadIdx.x;
  const int l = tid & 63;
  const int wv = tid >> 6;
  const int wr = wv >> 1, wc = wv & 1;
  const int row0 = blockIdx.x * 128;
  const int col0 = blockIdx.y * 128;

  f32x4 acc[4][4];
#pragma unroll
  for (int i = 0; i < 4; ++i)
#pragma unroll
    for (int j = 0; j < 4; ++j)
#pragma unroll
      for (int e = 0; e < 4; ++e) acc[i][j][e] = 0.f;

  for (int kb = 0; kb < CDIM; kb += 32) {
#pragma unroll
    for (int i = 0; i < 2; ++i) {
      int cid = tid + i * 256;
      int r = cid >> 2, c = cid & 3;
      uint4 v = *(const uint4*)&Xb[(size_t)(row0 + r) * CDIM + kb + c * 8];
      *(uint4*)&As[r * 32 + c * 8] = v;
      uint4 w = *(const uint4*)&Wb[(size_t)(col0 + r) * CDIM + kb + c * 8];
      *(uint4*)&Bs[r * 32 + c * 8] = w;
    }
    __syncthreads();
    bf16x8 af[4], bfr[4];
#pragma unroll
    for (int mt = 0; mt < 4; ++mt)
      af[mt] = *(const bf16x8*)&As[(wr * 64 + mt * 16 + (l & 15)) * 32 + (l >> 4) * 8];
#pragma unroll
    for (int nt = 0; nt < 4; ++nt)
      bfr[nt] = *(const bf16x8*)&Bs[(wc * 64 + nt * 16 + (l & 15)) * 32 + (l >> 4) * 8];
#pragma unroll
    for (int mt = 0; mt < 4; ++mt)
#pragma unroll
      for (int nt = 0; nt < 4; ++nt)
        acc[mt][nt] = __builtin_amdgcn_mfma_f32_16x16x32_bf16(af[mt], bfr[nt], acc[mt][nt], 0, 0, 0);
    __syncthreads();
  }

  const int slab = blockIdx.y / 3;
  const int cslab0 = col0 - slab * CDIM;
  float* dst = qslab + (size_t)slab * OUTSZ;
#pragma unroll
  for (int nt = 0; nt < 4; ++nt) {
    int colg = col0 + wc * 64 + nt * 16 + (l & 15);
    int colo = cslab0 + wc * 64 + nt * 16 + (l & 15);
    float bv = Bq[colg];
#pragma unroll
    for (int mt = 0; mt < 4; ++mt) {
      int rbase = row0 + wr * 64 + mt * 16 + (l >> 4) * 4;
#pragma unroll
      for (int j = 0; j < 4; ++j)
        dst[(size_t)(rbase + j) * CDIM + colo] = acc[mt][nt][j] + bv;
    }
  }
}

// ---------------------------------------------------------------------------
// Kernel 2 (v3): per-window attention, MFMA QK^T + PV, bf16 LDS pipeline.
// 512 threads = 8 waves. LDS regions:
//   SA  [49][49][16] bf16 (76.8KB): phase-A scores S[n][m][h] -> phase-D out P'[g][49][56]
//   PB  [12][49][56] bf16 (65.9KB): phase-B out P[g][n][m] (softmaxed in place)
//                                   -> reused after phase D as Vst[384][72]
//   aux: relidx u16 + rpb bf16
// 5 barriers/block. All MFMA pad regions proven finite (junk x V-zero = 0).
// ---------------------------------------------------------------------------
__launch_bounds__(512, 2)
__global__ void k_attn3(const float* __restrict__ qslab, const float* __restrict__ kslab,
                        const float* __restrict__ vslab, const float* __restrict__ mask,
                        const float* __restrict__ rpb, const int* __restrict__ relidx,
                        const float* __restrict__ plw, const float* __restrict__ plb,
                        const float* __restrict__ pww, const float* __restrict__ pwb,
                        float* __restrict__ xout) {
  __shared__ ushort_t SA[49 * 49 * 16];   // 76832 B
  __shared__ ushort_t PB[12 * 49 * 56];   // 65856 B
  __shared__ ushort_t ridx_s[2401];       // 4802 B
  __shared__ ushort_t rpbb[169 * 12];     // 4056 B

  const int tid = threadIdx.x;
  const int b = blockIdx.x;
  const size_t base = (size_t)b * TOK * CDIM;
  const int l = tid & 63, l15 = l & 15, l16 = l >> 4;
  const int wv = tid >> 6;                // 0..7
  const int rt = wv >> 1;                 // n-tile 0..3
  const int cs = (wv & 1) * 2;            // m-tile start (0 or 2)
  const float scale = 0.17677669529663687f;

  // aux preload (ordered before phase-B use by barrier 1)
  for (int i = tid; i < 2401; i += 512) ridx_s[i] = (ushort_t)relidx[i];
  for (int i = tid; i < 169 * 12; i += 512) rpbb[i] = f2bf(rpb[i]);

  // ---- Phase A: S[n][m][h] = scale * (q . k), fragments direct from global
  const int nrow = rt * 16 + l15;
  for (int h = 0; h < NH; ++h) {
    bf16x8 af = {0, 0, 0, 0, 0, 0, 0, 0};
    if (nrow < TOK) {
      const float4* qp = (const float4*)(qslab + base + (size_t)nrow * CDIM + h * HDIM + l16 * 8);
      af = pack8(qp[0], qp[1]);
    }
    f32x4 acc[2];
#pragma unroll
    for (int t = 0; t < 2; ++t) {
      int mrow = (cs + t) * 16 + l15;
      bf16x8 bf = {0, 0, 0, 0, 0, 0, 0, 0};
      if (mrow < TOK) {
        const float4* kp = (const float4*)(kslab + base + (size_t)mrow * CDIM + h * HDIM + l16 * 8);
        bf = pack8(kp[0], kp[1]);
      }
      f32x4 z = {0.f, 0.f, 0.f, 0.f};
      acc[t] = __builtin_amdgcn_mfma_f32_16x16x32_bf16(af, bf, z, 0, 0, 0);
    }
#pragma unroll
    for (int t = 0; t < 2; ++t)
#pragma unroll
      for (int j = 0; j < 4; ++j) {
        int nj = rt * 16 + l16 * 4 + j;
        int mm = (cs + t) * 16 + l15;
        if (nj < TOK && mm < TOK)
          SA[(nj * TOK + mm) * 16 + h] = f2bf(acc[t][j] * scale);
      }
  }
  __syncthreads();   // 1

  // ---- Phase B: bias + proj_l + mask; write P[g][n][m] (m-contig)
  const int wmask = b & (NWIN - 1);
  for (int p = tid; p < TOK * TOK; p += 512) {
    uint4 v0 = *(const uint4*)&SA[p * 16];
    uint2 v1 = *(const uint2*)&SA[p * 16 + 8];
    int rid = ridx_s[p];
    const ushort_t* bp = &rpbb[rid * 12];
    uint2 b0 = *(const uint2*)&bp[0];
    uint2 b1 = *(const uint2*)&bp[4];
    uint2 b2 = *(const uint2*)&bp[8];
    float sh[12];
    sh[0]  = bf2f(v0.x) + bf2f(b0.x);  sh[1]  = bf2f(v0.x >> 16) + bf2f(b0.x >> 16);
    sh[2]  = bf2f(v0.y) + bf2f(b0.y);  sh[3]  = bf2f(v0.y >> 16) + bf2f(b0.y >> 16);
    sh[4]  = bf2f(v0.z) + bf2f(b1.x);  sh[5]  = bf2f(v0.z >> 16) + bf2f(b1.x >> 16);
    sh[6]  = bf2f(v0.w) + bf2f(b1.y);  sh[7]  = bf2f(v0.w >> 16) + bf2f(b1.y >> 16);
    sh[8]  = bf2f(v1.x) + bf2f(b2.x);  sh[9]  = bf2f(v1.x >> 16) + bf2f(b2.x >> 16);
    sh[10] = bf2f(v1.y) + bf2f(b2.y);  sh[11] = bf2f(v1.y >> 16) + bf2f(b2.y >> 16);
    float mk = mask[wmask * (TOK * TOK) + p];
    int n = p / TOK, m = p - n * TOK;
    int off = n * 56 + m;
#pragma unroll
    for (int g = 0; g < NH; ++g) {
      float o = plb[g] + mk;
#pragma unroll
      for (int hh = 0; hh < NH; ++hh) o = fmaf(plw[g * NH + hh], sh[hh], o);
      PB[g * 2744 + off] = f2bf(o);
    }
  }
  __syncthreads();   // 2

  // ---- Phase C: softmax over m (588 rows, contiguous bf16)
  for (int r = tid; r < NH * TOK; r += 512) {
    int g = r / TOK, n = r - g * TOK;
    ushort_t* row = &PB[g * 2744 + n * 56];
    float x[49];
#pragma unroll
    for (int m4 = 0; m4 < 12; ++m4) {
      uint2 u = *(const uint2*)&row[m4 * 4];
      x[m4 * 4 + 0] = bf2f(u.x); x[m4 * 4 + 1] = bf2f(u.x >> 16);
      x[m4 * 4 + 2] = bf2f(u.y); x[m4 * 4 + 3] = bf2f(u.y >> 16);
    }
    x[48] = bf2f(row[48]);
    float mx = x[0];
#pragma unroll
    for (int m = 1; m < TOK; ++m) mx = fmaxf(mx, x[m]);
    float s = 0.f;
#pragma unroll
    for (int m = 0; m < TOK; ++m) { x[m] = __expf(x[m] - mx); s += x[m]; }
    float inv = 1.f / s;
#pragma unroll
    for (int m4 = 0; m4 < 12; ++m4) {
      uint2 u;
      u.x = (uint32)f2bf(x[m4 * 4 + 0] * inv) | ((uint32)f2bf(x[m4 * 4 + 1] * inv) << 16);
      u.y = (uint32)f2bf(x[m4 * 4 + 2] * inv) | ((uint32)f2bf(x[m4 * 4 + 3] * inv) << 16);
      *(uint2*)&row[m4 * 4] = u;
    }
    row[48] = f2bf(x[48] * inv);
  }
  __syncthreads();   // 3

  // ---- Phase D: proj_w; write P'[g][n][m] into SA region (PV layout)
  for (int p = tid; p < TOK * TOK; p += 512) {
    int n = p / TOK, m = p - n * TOK;
    int off = n * 56 + m;
    float sh[12];
#pragma unroll
    for (int g = 0; g < NH; ++g) sh[g] = bf2f((uint32)PB[g * 2744 + off]);
#pragma unroll
    for (int g = 0; g < NH; ++g) {
      float o = pwb[g];
#pragma unroll
      for (int hh = 0; hh < NH; ++hh) o = fmaf(pww[g * NH + hh], sh[hh], o);
      SA[g * 2744 + off] = f2bf(o);
    }
  }
  // zero P' pad cols 49..55 (uninit LDS could be NaN; NaN*0 = NaN would poison PV)
  for (int i = tid; i < NH * TOK * 7; i += 512) {
    int gn = i / 7, mm = 49 + i - (i / 7) * 7;
    SA[gn * 56 + mm] = 0;
  }
  __syncthreads();   // 4

  // ---- Vst staging into PB region: Vst[c][m], stride 72, rows m>=49 zero
  ushort_t* Vst = PB;
  for (int i = tid; i < CDIM * 16; i += 512) {
    int c = i % CDIM, mq = i / CDIM;      // consecutive lanes -> consecutive c
    float f[4];
#pragma unroll
    for (int jj = 0; jj < 4; ++jj) {
      int m = mq * 4 + jj;
      f[jj] = (m < TOK) ? vslab[base + (size_t)m * CDIM + c] : 0.f;
    }
    uint2 u;
    u.x = (uint32)f2bf(f[0]) | ((uint32)f2bf(f[1]) << 16);
    u.y = (uint32)f2bf(f[2]) | ((uint32)f2bf(f[3]) << 16);
    *(uint2*)&Vst[c * 72 + mq * 4] = u;
  }
  __syncthreads();   // 5

  // ---- Phase E: PV via MFMA. out[n, g*32+d] = sum_m P'[g][n][m] * V[m, g*32+d]
  const int dt = wv & 1;
#pragma unroll 2
  for (int g = 0; g < NH; ++g) {
    f32x4 acc = {0.f, 0.f, 0.f, 0.f};
#pragma unroll
    for (int ks = 0; ks < 2; ++ks) {
      bf16x8 pa = *(const bf16x8*)&SA[g * 2744 + (rt * 16 + l15) * 56 + ks * 32 + l16 * 8];
      bf16x8 vb = *(const bf16x8*)&Vst[(g * HDIM + dt * 16 + l15) * 72 + ks * 32 + l16 * 8];
      acc = __builtin_amdgcn_mfma_f32_16x16x32_bf16(pa, vb, acc, 0, 0, 0);
    }
#pragma unroll
    for (int j = 0; j < 4; ++j) {
      int n = rt * 16 + l16 * 4 + j;
      if (n < TOK)
        xout[base + (size_t)n * CDIM + g * HDIM + dt * 16 + l15] = acc[j];
    }
  }
}

// ---------------------------------------------------------------------------
// Kernel 3: output projection, bf16 MFMA, in-place (unchanged from round 2).
// ---------------------------------------------------------------------------
__launch_bounds__(512)
__global__ void k_proj_mfma(float* __restrict__ Y, const float* __restrict__ W,
                            const float* __restrict__ Bv) {
  __shared__ ushort_t Asb[128 * 392];
  __shared__ ushort_t Bsb[384 * 40];
  const int tid = threadIdx.x;
  const int l = tid & 63;
  const int wv = tid >> 6;
  const int wr = wv >> 2, wc = wv & 3;
  const int row0 = blockIdx.x * 128;

#pragma unroll
  for (int i = 0; i < 12; ++i) {
    int cid = tid + i * 512;
    int r = cid / 48, c8 = cid % 48;
    const float4* s = (const float4*)&Y[(size_t)(row0 + r) * CDIM + c8 * 8];
    float4 a = s[0], b = s[1];
    uint4 o;
    o.x = (uint32)f2bf(a.x) | ((uint32)f2bf(a.y) << 16);
    o.y = (uint32)f2bf(a.z) | ((uint32)f2bf(a.w) << 16);
    o.z = (uint32)f2bf(b.x) | ((uint32)f2bf(b.y) << 16);
    o.w = (uint32)f2bf(b.z) | ((uint32)f2bf(b.w) << 16);
    *(uint4*)&Asb[r * 392 + c8 * 8] = o;
  }

  f32x4 acc[4][6];
#pragma unroll
  for (int i = 0; i < 4; ++i)
#pragma unroll
    for (int j = 0; j < 6; ++j)
#pragma unroll
      for (int e = 0; e < 4; ++e) acc[i][j][e] = 0.f;

  for (int kb = 0; kb < CDIM; kb += 32) {
    __syncthreads();
#pragma unroll
    for (int i = 0; i < 3; ++i) {
      int cid = tid + i * 512;
      int col = cid >> 2, k8 = cid & 3;
      const float4* s = (const float4*)&W[(size_t)col * CDIM + kb + k8 * 8];
      float4 a = s[0], b = s[1];
      uint4 o;
      o.x = (uint32)f2bf(a.x) | ((uint32)f2bf(a.y) << 16);
      o.y = (uint32)f2bf(a.z) | ((uint32)f2bf(a.w) << 16);
      o.z = (uint32)f2bf(b.x) | ((uint32)f2bf(b.y) << 16);
      o.w = (uint32)f2bf(b.z) | ((uint32)f2bf(b.w) << 16);
      *(uint4*)&Bsb[col * 40 + k8 * 8] = o;
    }
    __syncthreads();
    bf16x8 af[4], bfr[6];
#pragma unroll
    for (int mt = 0; mt < 4; ++mt)
      af[mt] = *(const bf16x8*)&Asb[(wr * 64 + mt * 16 + (l & 15)) * 392 + kb + (l >> 4) * 8];
#pragma unroll
    for (int nt = 0; nt < 6; ++nt)
      bfr[nt] = *(const bf16x8*)&Bsb[(wc * 96 + nt * 16 + (l & 15)) * 40 + (l >> 4) * 8];
#pragma unroll
    for (int mt = 0; mt < 4; ++mt)
#pragma unroll
      for (int nt = 0; nt < 6; ++nt)
        acc[mt][nt] = __builtin_amdgcn_mfma_f32_16x16x32_bf16(af[mt], bfr[nt], acc[mt][nt], 0, 0, 0);
  }

#pragma unroll
  for (int nt = 0; nt < 6; ++nt) {
    int col = wc * 96 + nt * 16 + (l & 15);
    float bv = Bv[col];
#pragma unroll
    for (int mt = 0; mt < 4; ++mt) {
      int rbase = row0 + wr * 64 + mt * 16 + (l >> 4) * 4;
#pragma unroll
      for (int j = 0; j < 4; ++j)
        Y[(size_t)(rbase + j) * CDIM + col] = acc[mt][nt][j] + bv;
    }
  }
}

// ---------------------------------------------------------------------------
extern "C" void kernel_launch(void* const* d_in, const int* in_sizes, int n_in,
                              void* d_out, int out_size, void* d_ws, size_t ws_size,
                              hipStream_t stream) {
  const float* x      = (const float*)d_in[0];
  const float* mask   = (const float*)d_in[1];
  const float* qkv_w  = (const float*)d_in[2];
  const float* qkv_b  = (const float*)d_in[3];
  const float* rpb    = (const float*)d_in[4];
  const float* plw    = (const float*)d_in[5];
  const float* plb    = (const float*)d_in[6];
  const float* pww    = (const float*)d_in[7];
  const float* pwb    = (const float*)d_in[8];
  const float* projw  = (const float*)d_in[9];
  const float* projb  = (const float*)d_in[10];
  const int*   relidx = (const int*)d_in[11];

  float* out   = (float*)d_out;
  float* qslab = out + (size_t)OUTSZ;
  float* kslab = out + 2 * (size_t)OUTSZ;
  float* vslab = out + 3 * (size_t)OUTSZ;

  ushort_t* Xb = (ushort_t*)out;                    // bf16 scratch in out slab
  ushort_t* Wb = (ushort_t*)(out + 70000000);

  k_cvt<<<(OUTSZ / 8 + 255) / 256, 256, 0, stream>>>(x, Xb, OUTSZ / 8);
  k_cvt<<<(3 * CDIM * CDIM / 8 + 255) / 256, 256, 0, stream>>>(qkv_w, Wb, 3 * CDIM * CDIM / 8);

  dim3 g1(BTOT * TOK / 128, (3 * CDIM) / 128);
  k_qkv_mfma<<<g1, 256, 0, stream>>>(Xb, Wb, qkv_b, qslab);

  k_attn3<<<BTOT, 512, 0, stream>>>(qslab, kslab, vslab, mask, rpb, relidx,
                                    plw, plb, pww, pwb, out);

  k_proj_mfma<<<BTOT * TOK / 128, 512, 0, stream>>>(out, projw, projb);
}

// Round 4
// 1773.602 us; speedup vs baseline: 3.8671x; 1.0909x over previous
//
#include <hip/hip_runtime.h>
#include <hip/hip_bf16.h>

#define TOK 49
#define CDIM 384
#define NH 12
#define HDIM 32
#define NWIN 64
#define BTOT 4096
#define OUTSZ (BTOT * TOK * CDIM)   // 77,070,336 floats per slab

typedef __attribute__((ext_vector_type(8))) short bf16x8;
typedef __attribute__((ext_vector_type(4))) float f32x4;
typedef unsigned int uint32;
typedef unsigned short ushort_t;

__device__ inline ushort_t f2bf(float f) {          // RNE fp32 -> bf16
  uint32 u = __float_as_uint(f);
  u += 0x7FFF + ((u >> 16) & 1);
  return (ushort_t)(u >> 16);
}
__device__ inline float bf2f(uint32 u) { return __uint_as_float((u & 0xffffu) << 16); }

__device__ inline bf16x8 pack8(float4 a, float4 b) {
  union { __hip_bfloat162 h[4]; bf16x8 v; } u;
  u.h[0] = __float22bfloat162_rn(float2{a.x, a.y});
  u.h[1] = __float22bfloat162_rn(float2{a.z, a.w});
  u.h[2] = __float22bfloat162_rn(float2{b.x, b.y});
  u.h[3] = __float22bfloat162_rn(float2{b.z, b.w});
  return u.v;
}

// ---------------------------------------------------------------------------
// fp32 -> bf16 bulk convert
// ---------------------------------------------------------------------------
__global__ void k_cvt(const float* __restrict__ src, ushort_t* __restrict__ dst, int n8) {
  int i = blockIdx.x * 256 + threadIdx.x;
  if (i >= n8) return;
  const float4* s = (const float4*)(src + (size_t)i * 8);
  float4 a = s[0], b = s[1];
  uint4 o;
  o.x = (uint32)f2bf(a.x) | ((uint32)f2bf(a.y) << 16);
  o.y = (uint32)f2bf(a.z) | ((uint32)f2bf(a.w) << 16);
  o.z = (uint32)f2bf(b.x) | ((uint32)f2bf(b.y) << 16);
  o.w = (uint32)f2bf(b.z) | ((uint32)f2bf(b.w) << 16);
  *(uint4*)(dst + (size_t)i * 8) = o;
}

// ---------------------------------------------------------------------------
// Kernel 1: QKV GEMM, bf16 MFMA (unchanged; verified).
// ---------------------------------------------------------------------------
__launch_bounds__(256)
__global__ void k_qkv_mfma(const ushort_t* __restrict__ Xb, const ushort_t* __restrict__ Wb,
                           const float* __restrict__ Bq, float* __restrict__ qslab) {
  __shared__ ushort_t As[128 * 32];
  __shared__ ushort_t Bs[128 * 32];
  const int tid = threadIdx.x;
  const int l = tid & 63;
  const int wv = tid >> 6;
  const int wr = wv >> 1, wc = wv & 1;
  const int row0 = blockIdx.x * 128;
  const int col0 = blockIdx.y * 128;

  f32x4 acc[4][4];
#pragma unroll
  for (int i = 0; i < 4; ++i)
#pragma unroll
    for (int j = 0; j < 4; ++j)
#pragma unroll
      for (int e = 0; e < 4; ++e) acc[i][j][e] = 0.f;

  for (int kb = 0; kb < CDIM; kb += 32) {
#pragma unroll
    for (int i = 0; i < 2; ++i) {
      int cid = tid + i * 256;
      int r = cid >> 2, c = cid & 3;
      uint4 v = *(const uint4*)&Xb[(size_t)(row0 + r) * CDIM + kb + c * 8];
      *(uint4*)&As[r * 32 + c * 8] = v;
      uint4 w = *(const uint4*)&Wb[(size_t)(col0 + r) * CDIM + kb + c * 8];
      *(uint4*)&Bs[r * 32 + c * 8] = w;
    }
    __syncthreads();
    bf16x8 af[4], bfr[4];
#pragma unroll
    for (int mt = 0; mt < 4; ++mt)
      af[mt] = *(const bf16x8*)&As[(wr * 64 + mt * 16 + (l & 15)) * 32 + (l >> 4) * 8];
#pragma unroll
    for (int nt = 0; nt < 4; ++nt)
      bfr[nt] = *(const bf16x8*)&Bs[(wc * 64 + nt * 16 + (l & 15)) * 32 + (l >> 4) * 8];
#pragma unroll
    for (int mt = 0; mt < 4; ++mt)
#pragma unroll
      for (int nt = 0; nt < 4; ++nt)
        acc[mt][nt] = __builtin_amdgcn_mfma_f32_16x16x32_bf16(af[mt], bfr[nt], acc[mt][nt], 0, 0, 0);
    __syncthreads();
  }

  const int slab = blockIdx.y / 3;
  const int cslab0 = col0 - slab * CDIM;
  float* dst = qslab + (size_t)slab * OUTSZ;
#pragma unroll
  for (int nt = 0; nt < 4; ++nt) {
    int colg = col0 + wc * 64 + nt * 16 + (l & 15);
    int colo = cslab0 + wc * 64 + nt * 16 + (l & 15);
    float bv = Bq[colg];
#pragma unroll
    for (int mt = 0; mt < 4; ++mt) {
      int rbase = row0 + wr * 64 + mt * 16 + (l >> 4) * 4;
#pragma unroll
      for (int j = 0; j < 4; ++j)
        dst[(size_t)(rbase + j) * CDIM + colo] = acc[mt][nt][j] + bv;
    }
  }
}

// ---------------------------------------------------------------------------
// Kernel 2 (v4): per-window attention; 1024 threads = 16 waves (4/SIMD).
// Same LDS plan as v3: SA [49*49][16], PB [12][49][56] (-> Vst), aux.
// Wave tiling: phase A wave=(rt,ct) one 16x16 tile/head; phase E
// wave=(rt,dt,ghalf) 6 heads each. Grid-stride phases rescale to 1024.
// ---------------------------------------------------------------------------
__launch_bounds__(1024, 4)
__global__ void k_attn4(const float* __restrict__ qslab, const float* __restrict__ kslab,
                        const float* __restrict__ vslab, const float* __restrict__ mask,
                        const float* __restrict__ rpb, const int* __restrict__ relidx,
                        const float* __restrict__ plw, const float* __restrict__ plb,
                        const float* __restrict__ pww, const float* __restrict__ pwb,
                        float* __restrict__ xout) {
  __shared__ ushort_t SA[49 * 49 * 16];   // 76832 B
  __shared__ ushort_t PB[12 * 49 * 56];   // 65856 B
  __shared__ ushort_t ridx_s[2401];       // 4802 B
  __shared__ ushort_t rpbb[169 * 12];     // 4056 B

  const int tid = threadIdx.x;
  const int b = blockIdx.x;
  const size_t base = (size_t)b * TOK * CDIM;
  const int l = tid & 63, l15 = l & 15, l16 = l >> 4;
  const int wv = tid >> 6;                // 0..15
  const int rt = wv >> 2;                 // n-tile 0..3
  const int ct = wv & 3;                  // m-tile 0..3
  const float scale = 0.17677669529663687f;

  // aux preload (ordered before phase-B use by barrier 1)
  for (int i = tid; i < 2401; i += 1024) ridx_s[i] = (ushort_t)relidx[i];
  for (int i = tid; i < 169 * 12; i += 1024) rpbb[i] = f2bf(rpb[i]);

  // ---- Phase A: S[n][m][h] = scale * (q . k); one 16x16 tile per wave/head
  const int nrow = rt * 16 + l15;
  const int mrow = ct * 16 + l15;
  for (int h = 0; h < NH; ++h) {
    bf16x8 af = {0, 0, 0, 0, 0, 0, 0, 0};
    if (nrow < TOK) {
      const float4* qp = (const float4*)(qslab + base + (size_t)nrow * CDIM + h * HDIM + l16 * 8);
      af = pack8(qp[0], qp[1]);
    }
    bf16x8 bf = {0, 0, 0, 0, 0, 0, 0, 0};
    if (mrow < TOK) {
      const float4* kp = (const float4*)(kslab + base + (size_t)mrow * CDIM + h * HDIM + l16 * 8);
      bf = pack8(kp[0], kp[1]);
    }
    f32x4 z = {0.f, 0.f, 0.f, 0.f};
    f32x4 acc = __builtin_amdgcn_mfma_f32_16x16x32_bf16(af, bf, z, 0, 0, 0);
#pragma unroll
    for (int j = 0; j < 4; ++j) {
      int nj = rt * 16 + l16 * 4 + j;
      int mm = ct * 16 + l15;
      if (nj < TOK && mm < TOK)
        SA[(nj * TOK + mm) * 16 + h] = f2bf(acc[j] * scale);
    }
  }
  __syncthreads();   // 1

  // ---- Phase B: bias + proj_l + mask; write P[g][n][m] (m-contig)
  const int wmask = b & (NWIN - 1);
  for (int p = tid; p < TOK * TOK; p += 1024) {
    uint4 v0 = *(const uint4*)&SA[p * 16];
    uint2 v1 = *(const uint2*)&SA[p * 16 + 8];
    int rid = ridx_s[p];
    const ushort_t* bp = &rpbb[rid * 12];
    uint2 b0 = *(const uint2*)&bp[0];
    uint2 b1 = *(const uint2*)&bp[4];
    uint2 b2 = *(const uint2*)&bp[8];
    float sh[12];
    sh[0]  = bf2f(v0.x) + bf2f(b0.x);  sh[1]  = bf2f(v0.x >> 16) + bf2f(b0.x >> 16);
    sh[2]  = bf2f(v0.y) + bf2f(b0.y);  sh[3]  = bf2f(v0.y >> 16) + bf2f(b0.y >> 16);
    sh[4]  = bf2f(v0.z) + bf2f(b1.x);  sh[5]  = bf2f(v0.z >> 16) + bf2f(b1.x >> 16);
    sh[6]  = bf2f(v0.w) + bf2f(b1.y);  sh[7]  = bf2f(v0.w >> 16) + bf2f(b1.y >> 16);
    sh[8]  = bf2f(v1.x) + bf2f(b2.x);  sh[9]  = bf2f(v1.x >> 16) + bf2f(b2.x >> 16);
    sh[10] = bf2f(v1.y) + bf2f(b2.y);  sh[11] = bf2f(v1.y >> 16) + bf2f(b2.y >> 16);
    float mk = mask[wmask * (TOK * TOK) + p];
    int n = p / TOK, m = p - n * TOK;
    int off = n * 56 + m;
#pragma unroll
    for (int g = 0; g < NH; ++g) {
      float o = plb[g] + mk;
#pragma unroll
      for (int hh = 0; hh < NH; ++hh) o = fmaf(plw[g * NH + hh], sh[hh], o);
      PB[g * 2744 + off] = f2bf(o);
    }
  }
  __syncthreads();   // 2

  // ---- Phase C: softmax over m (588 rows, contiguous bf16)
  for (int r = tid; r < NH * TOK; r += 1024) {
    int g = r / TOK, n = r - g * TOK;
    ushort_t* row = &PB[g * 2744 + n * 56];
    float x[49];
#pragma unroll
    for (int m4 = 0; m4 < 12; ++m4) {
      uint2 u = *(const uint2*)&row[m4 * 4];
      x[m4 * 4 + 0] = bf2f(u.x); x[m4 * 4 + 1] = bf2f(u.x >> 16);
      x[m4 * 4 + 2] = bf2f(u.y); x[m4 * 4 + 3] = bf2f(u.y >> 16);
    }
    x[48] = bf2f(row[48]);
    float mx = x[0];
#pragma unroll
    for (int m = 1; m < TOK; ++m) mx = fmaxf(mx, x[m]);
    float s = 0.f;
#pragma unroll
    for (int m = 0; m < TOK; ++m) { x[m] = __expf(x[m] - mx); s += x[m]; }
    float inv = 1.f / s;
#pragma unroll
    for (int m4 = 0; m4 < 12; ++m4) {
      uint2 u;
      u.x = (uint32)f2bf(x[m4 * 4 + 0] * inv) | ((uint32)f2bf(x[m4 * 4 + 1] * inv) << 16);
      u.y = (uint32)f2bf(x[m4 * 4 + 2] * inv) | ((uint32)f2bf(x[m4 * 4 + 3] * inv) << 16);
      *(uint2*)&row[m4 * 4] = u;
    }
    row[48] = f2bf(x[48] * inv);
  }
  __syncthreads();   // 3

  // ---- Phase D: proj_w; write P'[g][n][m] into SA region (PV layout)
  for (int p = tid; p < TOK * TOK; p += 1024) {
    int n = p / TOK, m = p - n * TOK;
    int off = n * 56 + m;
    float sh[12];
#pragma unroll
    for (int g = 0; g < NH; ++g) sh[g] = bf2f((uint32)PB[g * 2744 + off]);
#pragma unroll
    for (int g = 0; g < NH; ++g) {
      float o = pwb[g];
#pragma unroll
      for (int hh = 0; hh < NH; ++hh) o = fmaf(pww[g * NH + hh], sh[hh], o);
      SA[g * 2744 + off] = f2bf(o);
    }
  }
  // zero P' pad cols 49..55 (uninit LDS could be NaN; NaN*0 = NaN would poison PV)
  for (int i = tid; i < NH * TOK * 7; i += 1024) {
    int gn = i / 7, mm = 49 + i - (i / 7) * 7;
    SA[gn * 56 + mm] = 0;
  }
  __syncthreads();   // 4

  // ---- Vst staging into PB region: Vst[c][m], stride 72, rows m>=49 zero
  ushort_t* Vst = PB;
  for (int i = tid; i < CDIM * 16; i += 1024) {
    int c = i % CDIM, mq = i / CDIM;      // consecutive lanes -> consecutive c
    float f[4];
#pragma unroll
    for (int jj = 0; jj < 4; ++jj) {
      int m = mq * 4 + jj;
      f[jj] = (m < TOK) ? vslab[base + (size_t)m * CDIM + c] : 0.f;
    }
    uint2 u;
    u.x = (uint32)f2bf(f[0]) | ((uint32)f2bf(f[1]) << 16);
    u.y = (uint32)f2bf(f[2]) | ((uint32)f2bf(f[3]) << 16);
    *(uint2*)&Vst[c * 72 + mq * 4] = u;
  }
  __syncthreads();   // 5

  // ---- Phase E: PV via MFMA; wave=(rt, dt, ghalf) -> 6 heads each
  const int dt = (wv >> 1) & 1;
  const int gh = wv & 1;
#pragma unroll 2
  for (int gi = 0; gi < 6; ++gi) {
    int g = gh * 6 + gi;
    f32x4 acc = {0.f, 0.f, 0.f, 0.f};
#pragma unroll
    for (int ks = 0; ks < 2; ++ks) {
      bf16x8 pa = *(const bf16x8*)&SA[g * 2744 + (rt * 16 + l15) * 56 + ks * 32 + l16 * 8];
      bf16x8 vb = *(const bf16x8*)&Vst[(g * HDIM + dt * 16 + l15) * 72 + ks * 32 + l16 * 8];
      acc = __builtin_amdgcn_mfma_f32_16x16x32_bf16(pa, vb, acc, 0, 0, 0);
    }
#pragma unroll
    for (int j = 0; j < 4; ++j) {
      int n = rt * 16 + l16 * 4 + j;
      if (n < TOK)
        xout[base + (size_t)n * CDIM + g * HDIM + dt * 16 + l15] = acc[j];
    }
  }
}

// ---------------------------------------------------------------------------
// Kernel 3: output projection, bf16 MFMA, in-place (unchanged; verified).
// ---------------------------------------------------------------------------
__launch_bounds__(512)
__global__ void k_proj_mfma(float* __restrict__ Y, const float* __restrict__ W,
                            const float* __restrict__ Bv) {
  __shared__ ushort_t Asb[128 * 392];
  __shared__ ushort_t Bsb[384 * 40];
  const int tid = threadIdx.x;
  const int l = tid & 63;
  const int wv = tid >> 6;
  const int wr = wv >> 2, wc = wv & 3;
  const int row0 = blockIdx.x * 128;

#pragma unroll
  for (int i = 0; i < 12; ++i) {
    int cid = tid + i * 512;
    int r = cid / 48, c8 = cid % 48;
    const float4* s = (const float4*)&Y[(size_t)(row0 + r) * CDIM + c8 * 8];
    float4 a = s[0], b = s[1];
    uint4 o;
    o.x = (uint32)f2bf(a.x) | ((uint32)f2bf(a.y) << 16);
    o.y = (uint32)f2bf(a.z) | ((uint32)f2bf(a.w) << 16);
    o.z = (uint32)f2bf(b.x) | ((uint32)f2bf(b.y) << 16);
    o.w = (uint32)f2bf(b.z) | ((uint32)f2bf(b.w) << 16);
    *(uint4*)&Asb[r * 392 + c8 * 8] = o;
  }

  f32x4 acc[4][6];
#pragma unroll
  for (int i = 0; i < 4; ++i)
#pragma unroll
    for (int j = 0; j < 6; ++j)
#pragma unroll
      for (int e = 0; e < 4; ++e) acc[i][j][e] = 0.f;

  for (int kb = 0; kb < CDIM; kb += 32) {
    __syncthreads();
#pragma unroll
    for (int i = 0; i < 3; ++i) {
      int cid = tid + i * 512;
      int col = cid >> 2, k8 = cid & 3;
      const float4* s = (const float4*)&W[(size_t)col * CDIM + kb + k8 * 8];
      float4 a = s[0], b = s[1];
      uint4 o;
      o.x = (uint32)f2bf(a.x) | ((uint32)f2bf(a.y) << 16);
      o.y = (uint32)f2bf(a.z) | ((uint32)f2bf(a.w) << 16);
      o.z = (uint32)f2bf(b.x) | ((uint32)f2bf(b.y) << 16);
      o.w = (uint32)f2bf(b.z) | ((uint32)f2bf(b.w) << 16);
      *(uint4*)&Bsb[col * 40 + k8 * 8] = o;
    }
    __syncthreads();
    bf16x8 af[4], bfr[6];
#pragma unroll
    for (int mt = 0; mt < 4; ++mt)
      af[mt] = *(const bf16x8*)&Asb[(wr * 64 + mt * 16 + (l & 15)) * 392 + kb + (l >> 4) * 8];
#pragma unroll
    for (int nt = 0; nt < 6; ++nt)
      bfr[nt] = *(const bf16x8*)&Bsb[(wc * 96 + nt * 16 + (l & 15)) * 40 + (l >> 4) * 8];
#pragma unroll
    for (int mt = 0; mt < 4; ++mt)
#pragma unroll
      for (int nt = 0; nt < 6; ++nt)
        acc[mt][nt] = __builtin_amdgcn_mfma_f32_16x16x32_bf16(af[mt], bfr[nt], acc[mt][nt], 0, 0, 0);
  }

#pragma unroll
  for (int nt = 0; nt < 6; ++nt) {
    int col = wc * 96 + nt * 16 + (l & 15);
    float bv = Bv[col];
#pragma unroll
    for (int mt = 0; mt < 4; ++mt) {
      int rbase = row0 + wr * 64 + mt * 16 + (l >> 4) * 4;
#pragma unroll
      for (int j = 0; j < 4; ++j)
        Y[(size_t)(rbase + j) * CDIM + col] = acc[mt][nt][j] + bv;
    }
  }
}

// ---------------------------------------------------------------------------
extern "C" void kernel_launch(void* const* d_in, const int* in_sizes, int n_in,
                              void* d_out, int out_size, void* d_ws, size_t ws_size,
                              hipStream_t stream) {
  const float* x      = (const float*)d_in[0];
  const float* mask   = (const float*)d_in[1];
  const float* qkv_w  = (const float*)d_in[2];
  const float* qkv_b  = (const float*)d_in[3];
  const float* rpb    = (const float*)d_in[4];
  const float* plw    = (const float*)d_in[5];
  const float* plb    = (const float*)d_in[6];
  const float* pww    = (const float*)d_in[7];
  const float* pwb    = (const float*)d_in[8];
  const float* projw  = (const float*)d_in[9];
  const float* projb  = (const float*)d_in[10];
  const int*   relidx = (const int*)d_in[11];

  float* out   = (float*)d_out;
  float* qslab = out + (size_t)OUTSZ;
  float* kslab = out + 2 * (size_t)OUTSZ;
  float* vslab = out + 3 * (size_t)OUTSZ;

  ushort_t* Xb = (ushort_t*)out;                    // bf16 scratch in out slab
  ushort_t* Wb = (ushort_t*)(out + 70000000);

  k_cvt<<<(OUTSZ / 8 + 255) / 256, 256, 0, stream>>>(x, Xb, OUTSZ / 8);
  k_cvt<<<(3 * CDIM * CDIM / 8 + 255) / 256, 256, 0, stream>>>(qkv_w, Wb, 3 * CDIM * CDIM / 8);

  dim3 g1(BTOT * TOK / 128, (3 * CDIM) / 128);
  k_qkv_mfma<<<g1, 256, 0, stream>>>(Xb, Wb, qkv_b, qslab);

  k_attn4<<<BTOT, 1024, 0, stream>>>(qslab, kslab, vslab, mask, rpb, relidx,
                                     plw, plb, pww, pwb, out);

  k_proj_mfma<<<BTOT * TOK / 128, 512, 0, stream>>>(out, projw, projb);
}

// Round 5
// 1643.606 us; speedup vs baseline: 4.1730x; 1.0791x over previous
//
#include <hip/hip_runtime.h>
#include <hip/hip_bf16.h>

#define TOK 49
#define NPT 2401                  // TOK*TOK
#define CDIM 384
#define NH 12
#define HDIM 32
#define NWIN 64
#define BTOT 4096
#define OUTSZ (BTOT * TOK * CDIM) // 77,070,336 floats per slab
#define L2E 1.4426950408889634f

typedef __attribute__((ext_vector_type(8))) short bf16x8;
typedef __attribute__((ext_vector_type(4))) float f32x4;
typedef unsigned int uint32;
typedef unsigned short ushort_t;

__device__ inline ushort_t f2bf(float f) {          // RNE fp32 -> bf16 (bulk cvt only)
  uint32 u = __float_as_uint(f);
  u += 0x7FFF + ((u >> 16) & 1);
  return (ushort_t)(u >> 16);
}
__device__ inline float bf2f(uint32 u) { return __uint_as_float((u & 0xffffu) << 16); }

__device__ inline uint32 pk2(float a, float b) {    // v_cvt_pk_bf16_f32
  union { __hip_bfloat162 h; uint32 u; } x;
  x.h = __float22bfloat162_rn(float2{a, b});
  return x.u;
}
__device__ inline bf16x8 pack8(float4 a, float4 b) {
  union { __hip_bfloat162 h[4]; bf16x8 v; } u;
  u.h[0] = __float22bfloat162_rn(float2{a.x, a.y});
  u.h[1] = __float22bfloat162_rn(float2{a.z, a.w});
  u.h[2] = __float22bfloat162_rn(float2{b.x, b.y});
  u.h[3] = __float22bfloat162_rn(float2{b.z, b.w});
  return u.v;
}
__device__ inline bf16x8 pack8f(const float* f) {
  union { __hip_bfloat162 h[4]; bf16x8 v; } u;
#pragma unroll
  for (int i = 0; i < 4; ++i) u.h[i] = __float22bfloat162_rn(float2{f[2*i], f[2*i+1]});
  return u.v;
}

// ---------------------------------------------------------------------------
// fp32 -> bf16 bulk convert
// ---------------------------------------------------------------------------
__global__ void k_cvt(const float* __restrict__ src, ushort_t* __restrict__ dst, int n8) {
  int i = blockIdx.x * 256 + threadIdx.x;
  if (i >= n8) return;
  const float4* s = (const float4*)(src + (size_t)i * 8);
  float4 a = s[0], b = s[1];
  uint4 o;
  o.x = (uint32)f2bf(a.x) | ((uint32)f2bf(a.y) << 16);
  o.y = (uint32)f2bf(a.z) | ((uint32)f2bf(a.w) << 16);
  o.z = (uint32)f2bf(b.x) | ((uint32)f2bf(b.y) << 16);
  o.w = (uint32)f2bf(b.z) | ((uint32)f2bf(b.w) << 16);
  *(uint4*)(dst + (size_t)i * 8) = o;
}

// ---------------------------------------------------------------------------
// biasmix[rid][16] = (plb[g] + sum_h plw[g,h]*rpb[rid,h]) * log2(e);  0 for g>=12
// ---------------------------------------------------------------------------
__global__ void k_bias(const float* __restrict__ rpb, const float* __restrict__ plw,
                       const float* __restrict__ plb, float* __restrict__ bm) {
  int i = blockIdx.x * 256 + threadIdx.x;
  if (i >= 169 * 16) return;
  int rid = i >> 4, g = i & 15;
  float s = 0.f;
  if (g < NH) {
    s = plb[g];
#pragma unroll
    for (int h = 0; h < NH; ++h) s = fmaf(plw[g * NH + h], rpb[rid * NH + h], s);
    s *= L2E;
  }
  bm[i] = s;
}

// ---------------------------------------------------------------------------
// Kernel 1: QKV GEMM, bf16 MFMA (unchanged; verified).
// ---------------------------------------------------------------------------
__launch_bounds__(256)
__global__ void k_qkv_mfma(const ushort_t* __restrict__ Xb, const ushort_t* __restrict__ Wb,
                           const float* __restrict__ Bq, float* __restrict__ qslab) {
  __shared__ ushort_t As[128 * 32];
  __shared__ ushort_t Bs[128 * 32];
  const int tid = threadIdx.x;
  const int l = tid & 63;
  const int wv = tid >> 6;
  const int wr = wv >> 1, wc = wv & 1;
  const int row0 = blockIdx.x * 128;
  const int col0 = blockIdx.y * 128;

  f32x4 acc[4][4];
#pragma unroll
  for (int i = 0; i < 4; ++i)
#pragma unroll
    for (int j = 0; j < 4; ++j)
#pragma unroll
      for (int e = 0; e < 4; ++e) acc[i][j][e] = 0.f;

  for (int kb = 0; kb < CDIM; kb += 32) {
#pragma unroll
    for (int i = 0; i < 2; ++i) {
      int cid = tid + i * 256;
      int r = cid >> 2, c = cid & 3;
      uint4 v = *(const uint4*)&Xb[(size_t)(row0 + r) * CDIM + kb + c * 8];
      *(uint4*)&As[r * 32 + c * 8] = v;
      uint4 w = *(const uint4*)&Wb[(size_t)(col0 + r) * CDIM + kb + c * 8];
      *(uint4*)&Bs[r * 32 + c * 8] = w;
    }
    __syncthreads();
    bf16x8 af[4], bfr[4];
#pragma unroll
    for (int mt = 0; mt < 4; ++mt)
      af[mt] = *(const bf16x8*)&As[(wr * 64 + mt * 16 + (l & 15)) * 32 + (l >> 4) * 8];
#pragma unroll
    for (int nt = 0; nt < 4; ++nt)
      bfr[nt] = *(const bf16x8*)&Bs[(wc * 64 + nt * 16 + (l & 15)) * 32 + (l >> 4) * 8];
#pragma unroll
    for (int mt = 0; mt < 4; ++mt)
#pragma unroll
      for (int nt = 0; nt < 4; ++nt)
        acc[mt][nt] = __builtin_amdgcn_mfma_f32_16x16x32_bf16(af[mt], bfr[nt], acc[mt][nt], 0, 0, 0);
    __syncthreads();
  }

  const int slab = blockIdx.y / 3;
  const int cslab0 = col0 - slab * CDIM;
  float* dst = qslab + (size_t)slab * OUTSZ;
#pragma unroll
  for (int nt = 0; nt < 4; ++nt) {
    int colg = col0 + wc * 64 + nt * 16 + (l & 15);
    int colo = cslab0 + wc * 64 + nt * 16 + (l & 15);
    float bv = Bq[colg];
#pragma unroll
    for (int mt = 0; mt < 4; ++mt) {
      int rbase = row0 + wr * 64 + mt * 16 + (l >> 4) * 4;
#pragma unroll
      for (int j = 0; j < 4; ++j)
        dst[(size_t)(rbase + j) * CDIM + colo] = acc[mt][nt][j] + bv;
    }
  }
}

// ---------------------------------------------------------------------------
// Kernel 2 (v5): per-window attention; both head-mixes on the matrix pipe.
// 1024 threads = 16 waves. Regions:
//   R1 (76832B): SA[p][16] raw qk scores (h-contig)  ->  P' [12][49][56]
//   R2 (65856B): PB [12][49][56] pre-softmax (log2e-scaled) -> S2[p][12] -> Vst[384][72]
// Mix MFMAs use 16x16x32 with K zero-padded in-register (no new builtins).
// Barriers: [aux+A] b1 [B] b2 [C-read] b3 [C-write S2] b4 [D] b5 [Vst] b6 [E]
// ---------------------------------------------------------------------------
__launch_bounds__(1024, 4)
__global__ void k_attn5(const float* __restrict__ qslab, const float* __restrict__ kslab,
                        const float* __restrict__ vslab, const float* __restrict__ mask,
                        const float* __restrict__ bmg, const int* __restrict__ relidx,
                        const float* __restrict__ plw, const float* __restrict__ pww,
                        const float* __restrict__ pwb, float* __restrict__ xout) {
  __shared__ __align__(16) ushort_t R1[38416];   // 76832 B
  __shared__ __align__(16) ushort_t R2[32928];   // 65856 B
  __shared__ float bm_s[169 * 16];               // 10816 B
  __shared__ ushort_t ridx_s[2402];
  __shared__ ushort_t offtab[2402];

  const int tid = threadIdx.x;
  const int b = blockIdx.x;
  const size_t base = (size_t)b * TOK * CDIM;
  const int l = tid & 63, l15 = l & 15, l16 = l >> 4;
  const int wv = tid >> 6;                // 0..15
  const int rt = wv >> 2;                 // n-tile 0..3 (A & E)
  const int ct = wv & 3;                  // m-tile 0..3 (A)

  // ---- preload aux + zero SA h-pads (slots 12..15 of every point)
  for (int i = tid; i < 169 * 16; i += 1024) bm_s[i] = bmg[i];
  for (int i = tid; i < NPT; i += 1024) {
    ridx_s[i] = (ushort_t)relidx[i];
    int nn = (int)((float)i * 0.02040816326f + 1e-4f);
    offtab[i] = (ushort_t)(nn * 56 + (i - nn * TOK));
    *(uint32*)&R1[i * 16 + 12] = 0u;
    *(uint32*)&R1[i * 16 + 14] = 0u;
  }

  // ---- Phase A: SA[p][h] = raw q.k (scale folded into mix B-frag)
  {
    const int nrow = rt * 16 + l15;
    const int mrow = ct * 16 + l15;
    for (int h = 0; h < NH; ++h) {
      bf16x8 af = {0,0,0,0,0,0,0,0}, bf = {0,0,0,0,0,0,0,0};
      if (nrow < TOK) {
        const float4* qp = (const float4*)(qslab + base + (size_t)nrow * CDIM + h * HDIM + l16 * 8);
        af = pack8(qp[0], qp[1]);
      }
      if (mrow < TOK) {
        const float4* kp = (const float4*)(kslab + base + (size_t)mrow * CDIM + h * HDIM + l16 * 8);
        bf = pack8(kp[0], kp[1]);
      }
      f32x4 z = {0.f, 0.f, 0.f, 0.f};
      f32x4 s = __builtin_amdgcn_mfma_f32_16x16x32_bf16(af, bf, z, 0, 0, 0);
      uint32 s01 = pk2(s[0], s[1]);
      uint32 s23 = pk2(s[2], s[3]);
      ushort_t us[4] = {(ushort_t)s01, (ushort_t)(s01 >> 16), (ushort_t)s23, (ushort_t)(s23 >> 16)};
#pragma unroll
      for (int j = 0; j < 4; ++j) {
        int nj = rt * 16 + l16 * 4 + j;
        if (nj < TOK && mrow < TOK) R1[(nj * TOK + mrow) * 16 + h] = us[j];
      }
    }
  }
  __syncthreads();   // b1

  // ---- Phase B: mix1 via MFMA.  PB[p][g] = SA[p][:] @ (plw*scale*L2E)^T + C
  //      C-init = biasmix'[rid[p]][g] + mask[w][p]*L2E
  {
    const float SCL = 0.17677669529663687f * L2E;
    float pf[8];
#pragma unroll
    for (int j = 0; j < 8; ++j) {
      int kj = l16 * 8 + j;
      pf[j] = (l16 < 2 && l15 < NH && kj < NH) ? plw[l15 * NH + kj] * SCL : 0.f;
    }
    bf16x8 bfrag = pack8f(pf);
    const float* maskw = mask + (size_t)(b & (NWIN - 1)) * NPT;
    for (int t = wv; t < 151; t += 16) {
      int pa = t * 16 + l15; if (pa > 2400) pa = 2400;
      bf16x8 afrag = {0,0,0,0,0,0,0,0};
      if (l16 < 2) afrag = *(const bf16x8*)&R1[pa * 16 + l16 * 8];
      f32x4 cini;
      const int pj0 = t * 16 + l16 * 4;
#pragma unroll
      for (int j = 0; j < 4; ++j) {
        int p = pj0 + j; if (p > 2400) p = 2400;
        cini[j] = bm_s[(int)ridx_s[p] * 16 + l15] + maskw[p] * L2E;
      }
      f32x4 o = __builtin_amdgcn_mfma_f32_16x16x32_bf16(afrag, bfrag, cini, 0, 0, 0);
      if (l15 < NH) {
        uint32 q01 = pk2(o[0], o[1]);
        uint32 q23 = pk2(o[2], o[3]);
        ushort_t us[4] = {(ushort_t)q01, (ushort_t)(q01 >> 16), (ushort_t)q23, (ushort_t)(q23 >> 16)};
#pragma unroll
        for (int j = 0; j < 4; ++j) {
          int p = pj0 + j;
          if (p < NPT) R2[l15 * 2744 + (int)offtab[p]] = us[j];
        }
      }
    }
  }
  __syncthreads();   // b2

  // ---- Phase C: softmax rows (values are x*log2e -> exp2 direct).
  float xv[49];
  int cg = 0, cn = 0;
  const bool has = tid < NH * TOK;
  if (has) {
    cg = (int)((float)tid * 0.02040816326f + 1e-4f);
    cn = tid - cg * TOK;
    const ushort_t* row = &R2[cg * 2744 + cn * 56];
    const uint2* r2 = (const uint2*)row;
#pragma unroll
    for (int q = 0; q < 12; ++q) {
      uint2 u = r2[q];
      xv[q * 4 + 0] = bf2f(u.x); xv[q * 4 + 1] = bf2f(u.x >> 16);
      xv[q * 4 + 2] = bf2f(u.y); xv[q * 4 + 3] = bf2f(u.y >> 16);
    }
    xv[48] = bf2f(row[48]);
    float mx = xv[0];
#pragma unroll
    for (int m = 1; m < TOK; ++m) mx = fmaxf(mx, xv[m]);
    float s = 0.f;
#pragma unroll
    for (int m = 0; m < TOK; ++m) { xv[m] = exp2f(xv[m] - mx); s += xv[m]; }
    float inv = 1.f / s;
#pragma unroll
    for (int m = 0; m < TOK; ++m) xv[m] *= inv;
  }
  __syncthreads();   // b3 (all PB reads done; R2 now reusable as S2)

  if (has) {
    ushort_t* s2 = &R2[(cn * TOK) * 12 + cg];   // S2[p][12], p = cn*49 + m
#pragma unroll
    for (int m = 0; m < 48; m += 2) {
      uint32 pk = pk2(xv[m], xv[m + 1]);
      s2[m * 12]      = (ushort_t)pk;
      s2[m * 12 + 12] = (ushort_t)(pk >> 16);
    }
    s2[48 * 12] = (ushort_t)pk2(xv[48], 0.f);
  }
  __syncthreads();   // b4

  // ---- Phase D: mix2 via MFMA.  P'[p][g] = S2[p][:] @ pww^T + pwb
  {
    float pf[8];
#pragma unroll
    for (int j = 0; j < 8; ++j) {
      int kj = l16 * 8 + j;
      pf[j] = (l16 < 2 && l15 < NH && kj < NH) ? pww[l15 * NH + kj] : 0.f;
    }
    bf16x8 bfrag = pack8f(pf);
    const float pwbv = (l15 < NH) ? pwb[l15] : 0.f;
    const f32x4 cini = {pwbv, pwbv, pwbv, pwbv};
    for (int t = wv; t < 151; t += 16) {
      int pa = t * 16 + l15;                       // <=2415; reads stay in R2
      bf16x8 afrag = {0,0,0,0,0,0,0,0};
      if (l16 < 2) {
        union { uint32 u[4]; bf16x8 v; } ua;
        uint2 lo = *(const uint2*)&R2[pa * 12 + l16 * 8];
        uint2 hi = *(const uint2*)&R2[pa * 12 + l16 * 8 + 4];
        ua.u[0] = lo.x; ua.u[1] = lo.y; ua.u[2] = hi.x; ua.u[3] = hi.y;
        afrag = ua.v;
      }
      f32x4 o = __builtin_amdgcn_mfma_f32_16x16x32_bf16(afrag, bfrag, cini, 0, 0, 0);
      if (l15 < NH) {
        uint32 q01 = pk2(o[0], o[1]);
        uint32 q23 = pk2(o[2], o[3]);
        ushort_t us[4] = {(ushort_t)q01, (ushort_t)(q01 >> 16), (ushort_t)q23, (ushort_t)(q23 >> 16)};
        const int pj0 = t * 16 + l16 * 4;
#pragma unroll
        for (int j = 0; j < 4; ++j) {
          int p = pj0 + j;
          if (p < NPT) R1[l15 * 2744 + (int)offtab[p]] = us[j];
        }
      }
    }
    // zero P' pad cols m=49..55 (NaN-safety for PV K-pad)
    for (int i = tid; i < NH * TOK * 7; i += 1024) {
      int g = i / 343; int r = i - g * 343; int n2 = r / 7; int m2 = r - n2 * 7;
      R1[g * 2744 + n2 * 56 + 49 + m2] = 0;
    }
  }
  __syncthreads();   // b5

  // ---- Vst staging into R2: Vst[c][m], stride 72, rows m>=49 zero
  for (int i = tid; i < CDIM * 16; i += 1024) {
    int mq = i / CDIM, c = i - mq * CDIM;
    float f0 = 0.f, f1 = 0.f, f2 = 0.f, f3 = 0.f;
    int m = mq * 4;
    if (m     < TOK) f0 = vslab[base + (size_t)(m    ) * CDIM + c];
    if (m + 1 < TOK) f1 = vslab[base + (size_t)(m + 1) * CDIM + c];
    if (m + 2 < TOK) f2 = vslab[base + (size_t)(m + 2) * CDIM + c];
    if (m + 3 < TOK) f3 = vslab[base + (size_t)(m + 3) * CDIM + c];
    uint2 u;
    u.x = pk2(f0, f1);
    u.y = pk2(f2, f3);
    *(uint2*)&R2[c * 72 + mq * 4] = u;
  }
  __syncthreads();   // b6

  // ---- Phase E: PV via MFMA; wave=(rt, dt, gh) -> 6 heads each
  const int dt = (wv >> 1) & 1;
  const int gh = wv & 1;
#pragma unroll 2
  for (int gi = 0; gi < 6; ++gi) {
    int g = gh * 6 + gi;
    f32x4 acc = {0.f, 0.f, 0.f, 0.f};
#pragma unroll
    for (int ks = 0; ks < 2; ++ks) {
      bf16x8 pa8 = *(const bf16x8*)&R1[g * 2744 + (rt * 16 + l15) * 56 + ks * 32 + l16 * 8];
      bf16x8 vb8 = *(const bf16x8*)&R2[(g * HDIM + dt * 16 + l15) * 72 + ks * 32 + l16 * 8];
      acc = __builtin_amdgcn_mfma_f32_16x16x32_bf16(pa8, vb8, acc, 0, 0, 0);
    }
#pragma unroll
    for (int j = 0; j < 4; ++j) {
      int n = rt * 16 + l16 * 4 + j;
      if (n < TOK)
        xout[base + (size_t)n * CDIM + g * HDIM + dt * 16 + l15] = acc[j];
    }
  }
}

// ---------------------------------------------------------------------------
// Kernel 3: output projection, bf16 MFMA, in-place (unchanged; verified).
// ---------------------------------------------------------------------------
__launch_bounds__(512)
__global__ void k_proj_mfma(float* __restrict__ Y, const float* __restrict__ W,
                            const float* __restrict__ Bv) {
  __shared__ ushort_t Asb[128 * 392];
  __shared__ ushort_t Bsb[384 * 40];
  const int tid = threadIdx.x;
  const int l = tid & 63;
  const int wv = tid >> 6;
  const int wr = wv >> 2, wc = wv & 3;
  const int row0 = blockIdx.x * 128;

#pragma unroll
  for (int i = 0; i < 12; ++i) {
    int cid = tid + i * 512;
    int r = cid / 48, c8 = cid % 48;
    const float4* s = (const float4*)&Y[(size_t)(row0 + r) * CDIM + c8 * 8];
    float4 a = s[0], b = s[1];
    uint4 o;
    o.x = (uint32)f2bf(a.x) | ((uint32)f2bf(a.y) << 16);
    o.y = (uint32)f2bf(a.z) | ((uint32)f2bf(a.w) << 16);
    o.z = (uint32)f2bf(b.x) | ((uint32)f2bf(b.y) << 16);
    o.w = (uint32)f2bf(b.z) | ((uint32)f2bf(b.w) << 16);
    *(uint4*)&Asb[r * 392 + c8 * 8] = o;
  }

  f32x4 acc[4][6];
#pragma unroll
  for (int i = 0; i < 4; ++i)
#pragma unroll
    for (int j = 0; j < 6; ++j)
#pragma unroll
      for (int e = 0; e < 4; ++e) acc[i][j][e] = 0.f;

  for (int kb = 0; kb < CDIM; kb += 32) {
    __syncthreads();
#pragma unroll
    for (int i = 0; i < 3; ++i) {
      int cid = tid + i * 512;
      int col = cid >> 2, k8 = cid & 3;
      const float4* s = (const float4*)&W[(size_t)col * CDIM + kb + k8 * 8];
      float4 a = s[0], b = s[1];
      uint4 o;
      o.x = (uint32)f2bf(a.x) | ((uint32)f2bf(a.y) << 16);
      o.y = (uint32)f2bf(a.z) | ((uint32)f2bf(a.w) << 16);
      o.z = (uint32)f2bf(b.x) | ((uint32)f2bf(b.y) << 16);
      o.w = (uint32)f2bf(b.z) | ((uint32)f2bf(b.w) << 16);
      *(uint4*)&Bsb[col * 40 + k8 * 8] = o;
    }
    __syncthreads();
    bf16x8 af[4], bfr[6];
#pragma unroll
    for (int mt = 0; mt < 4; ++mt)
      af[mt] = *(const bf16x8*)&Asb[(wr * 64 + mt * 16 + (l & 15)) * 392 + kb + (l >> 4) * 8];
#pragma unroll
    for (int nt = 0; nt < 6; ++nt)
      bfr[nt] = *(const bf16x8*)&Bsb[(wc * 96 + nt * 16 + (l & 15)) * 40 + (l >> 4) * 8];
#pragma unroll
    for (int mt = 0; mt < 4; ++mt)
#pragma unroll
      for (int nt = 0; nt < 6; ++nt)
        acc[mt][nt] = __builtin_amdgcn_mfma_f32_16x16x32_bf16(af[mt], bfr[nt], acc[mt][nt], 0, 0, 0);
  }

#pragma unroll
  for (int nt = 0; nt < 6; ++nt) {
    int col = wc * 96 + nt * 16 + (l & 15);
    float bv = Bv[col];
#pragma unroll
    for (int mt = 0; mt < 4; ++mt) {
      int rbase = row0 + wr * 64 + mt * 16 + (l >> 4) * 4;
#pragma unroll
      for (int j = 0; j < 4; ++j)
        Y[(size_t)(rbase + j) * CDIM + col] = acc[mt][nt][j] + bv;
    }
  }
}

// ---------------------------------------------------------------------------
extern "C" void kernel_launch(void* const* d_in, const int* in_sizes, int n_in,
                              void* d_out, int out_size, void* d_ws, size_t ws_size,
                              hipStream_t stream) {
  const float* x      = (const float*)d_in[0];
  const float* mask   = (const float*)d_in[1];
  const float* qkv_w  = (const float*)d_in[2];
  const float* qkv_b  = (const float*)d_in[3];
  const float* rpb    = (const float*)d_in[4];
  const float* plw    = (const float*)d_in[5];
  const float* plb    = (const float*)d_in[6];
  const float* pww    = (const float*)d_in[7];
  const float* pwb    = (const float*)d_in[8];
  const float* projw  = (const float*)d_in[9];
  const float* projb  = (const float*)d_in[10];
  const int*   relidx = (const int*)d_in[11];

  float* out   = (float*)d_out;
  float* qslab = out + (size_t)OUTSZ;
  float* kslab = out + 2 * (size_t)OUTSZ;
  float* vslab = out + 3 * (size_t)OUTSZ;

  ushort_t* Xb = (ushort_t*)out;                    // bf16 scratch in out slab
  ushort_t* Wb = (ushort_t*)(out + 70000000);
  float*    bm = (float*)d_ws;                      // 169*16 f32 biasmix

  k_cvt<<<(OUTSZ / 8 + 255) / 256, 256, 0, stream>>>(x, Xb, OUTSZ / 8);
  k_cvt<<<(3 * CDIM * CDIM / 8 + 255) / 256, 256, 0, stream>>>(qkv_w, Wb, 3 * CDIM * CDIM / 8);
  k_bias<<<(169 * 16 + 255) / 256, 256, 0, stream>>>(rpb, plw, plb, bm);

  dim3 g1(BTOT * TOK / 128, (3 * CDIM) / 128);
  k_qkv_mfma<<<g1, 256, 0, stream>>>(Xb, Wb, qkv_b, qslab);

  k_attn5<<<BTOT, 1024, 0, stream>>>(qslab, kslab, vslab, mask, bm, relidx,
                                     plw, pww, pwb, out);

  k_proj_mfma<<<BTOT * TOK / 128, 512, 0, stream>>>(out, projw, projb);
}

// Round 7
// 1579.202 us; speedup vs baseline: 4.3432x; 1.0408x over previous
//
#include <hip/hip_runtime.h>
#include <hip/hip_bf16.h>

#define TOK 49
#define NPT 2401                  // TOK*TOK
#define CDIM 384
#define NH 12
#define HDIM 32
#define NWIN 64
#define BTOT 4096
#define OUTSZ (BTOT * TOK * CDIM) // 77,070,336 floats per slab
#define L2E 1.4426950408889634f

typedef __attribute__((ext_vector_type(8))) short bf16x8;
typedef __attribute__((ext_vector_type(4))) float f32x4;
typedef unsigned int uint32;
typedef unsigned short ushort_t;

__device__ inline ushort_t f2bf(float f) {          // RNE fp32 -> bf16 (bulk cvt only)
  uint32 u = __float_as_uint(f);
  u += 0x7FFF + ((u >> 16) & 1);
  return (ushort_t)(u >> 16);
}
__device__ inline uint32 pk2(float a, float b) {    // v_cvt_pk_bf16_f32
  union { __hip_bfloat162 h; uint32 u; } x;
  x.h = __float22bfloat162_rn(float2{a, b});
  return x.u;
}
__device__ inline bf16x8 pack8(float4 a, float4 b) {
  union { __hip_bfloat162 h[4]; bf16x8 v; } u;
  u.h[0] = __float22bfloat162_rn(float2{a.x, a.y});
  u.h[1] = __float22bfloat162_rn(float2{a.z, a.w});
  u.h[2] = __float22bfloat162_rn(float2{b.x, b.y});
  u.h[3] = __float22bfloat162_rn(float2{b.z, b.w});
  return u.v;
}
__device__ inline bf16x8 pack8f(const float* f) {
  union { __hip_bfloat162 h[4]; bf16x8 v; } u;
#pragma unroll
  for (int i = 0; i < 4; ++i) u.h[i] = __float22bfloat162_rn(float2{f[2*i], f[2*i+1]});
  return u.v;
}

// ---------------------------------------------------------------------------
// fp32 -> bf16 bulk convert
// ---------------------------------------------------------------------------
__global__ void k_cvt(const float* __restrict__ src, ushort_t* __restrict__ dst, int n8) {
  int i = blockIdx.x * 256 + threadIdx.x;
  if (i >= n8) return;
  const float4* s = (const float4*)(src + (size_t)i * 8);
  float4 a = s[0], b = s[1];
  uint4 o;
  o.x = (uint32)f2bf(a.x) | ((uint32)f2bf(a.y) << 16);
  o.y = (uint32)f2bf(a.z) | ((uint32)f2bf(a.w) << 16);
  o.z = (uint32)f2bf(b.x) | ((uint32)f2bf(b.y) << 16);
  o.w = (uint32)f2bf(b.z) | ((uint32)f2bf(b.w) << 16);
  *(uint4*)(dst + (size_t)i * 8) = o;
}

// ---------------------------------------------------------------------------
// biasmix[rid][16] = (plb[g] + sum_h plw[g,h]*rpb[rid,h]) * log2(e);  0 for g>=12
// ---------------------------------------------------------------------------
__global__ void k_bias(const float* __restrict__ rpb, const float* __restrict__ plw,
                       const float* __restrict__ plb, float* __restrict__ bm) {
  int i = blockIdx.x * 256 + threadIdx.x;
  if (i >= 169 * 16) return;
  int rid = i >> 4, g = i & 15;
  float s = 0.f;
  if (g < NH) {
    s = plb[g];
#pragma unroll
    for (int h = 0; h < NH; ++h) s = fmaf(plw[g * NH + h], rpb[rid * NH + h], s);
    s *= L2E;
  }
  bm[i] = s;
}

// ---------------------------------------------------------------------------
// Kernel 1: QKV GEMM, bf16 MFMA (unchanged; verified).
// ---------------------------------------------------------------------------
__launch_bounds__(256)
__global__ void k_qkv_mfma(const ushort_t* __restrict__ Xb, const ushort_t* __restrict__ Wb,
                           const float* __restrict__ Bq, float* __restrict__ qslab) {
  __shared__ ushort_t As[128 * 32];
  __shared__ ushort_t Bs[128 * 32];
  const int tid = threadIdx.x;
  const int l = tid & 63;
  const int wv = tid >> 6;
  const int wr = wv >> 1, wc = wv & 1;
  const int row0 = blockIdx.x * 128;
  const int col0 = blockIdx.y * 128;

  f32x4 acc[4][4];
#pragma unroll
  for (int i = 0; i < 4; ++i)
#pragma unroll
    for (int j = 0; j < 4; ++j)
#pragma unroll
      for (int e = 0; e < 4; ++e) acc[i][j][e] = 0.f;

  for (int kb = 0; kb < CDIM; kb += 32) {
#pragma unroll
    for (int i = 0; i < 2; ++i) {
      int cid = tid + i * 256;
      int r = cid >> 2, c = cid & 3;
      uint4 v = *(const uint4*)&Xb[(size_t)(row0 + r) * CDIM + kb + c * 8];
      *(uint4*)&As[r * 32 + c * 8] = v;
      uint4 w = *(const uint4*)&Wb[(size_t)(col0 + r) * CDIM + kb + c * 8];
      *(uint4*)&Bs[r * 32 + c * 8] = w;
    }
    __syncthreads();
    bf16x8 af[4], bfr[4];
#pragma unroll
    for (int mt = 0; mt < 4; ++mt)
      af[mt] = *(const bf16x8*)&As[(wr * 64 + mt * 16 + (l & 15)) * 32 + (l >> 4) * 8];
#pragma unroll
    for (int nt = 0; nt < 4; ++nt)
      bfr[nt] = *(const bf16x8*)&Bs[(wc * 64 + nt * 16 + (l & 15)) * 32 + (l >> 4) * 8];
#pragma unroll
    for (int mt = 0; mt < 4; ++mt)
#pragma unroll
      for (int nt = 0; nt < 4; ++nt)
        acc[mt][nt] = __builtin_amdgcn_mfma_f32_16x16x32_bf16(af[mt], bfr[nt], acc[mt][nt], 0, 0, 0);
    __syncthreads();
  }

  const int slab = blockIdx.y / 3;
  const int cslab0 = col0 - slab * CDIM;
  float* dst = qslab + (size_t)slab * OUTSZ;
#pragma unroll
  for (int nt = 0; nt < 4; ++nt) {
    int colg = col0 + wc * 64 + nt * 16 + (l & 15);
    int colo = cslab0 + wc * 64 + nt * 16 + (l & 15);
    float bv = Bq[colg];
#pragma unroll
    for (int mt = 0; mt < 4; ++mt) {
      int rbase = row0 + wr * 64 + mt * 16 + (l >> 4) * 4;
#pragma unroll
      for (int j = 0; j < 4; ++j)
        dst[(size_t)(rbase + j) * CDIM + colo] = acc[mt][nt][j] + bv;
    }
  }
}

// ---------------------------------------------------------------------------
// Kernel 2 (v6b): per-window attention; per-wave-row softmax, all-vector LDS.
// Fix vs v6: mix1/mix2 S/P fragments zero-filled for l16>=2 (K-slots 16..31
// of the 16x16x32 MFMA MUST be zero; unguarded reads crossed into the next
// LDS row -> 0*NaN poisoning). Tail rows 2401..2415 fully zeroed.
// ---------------------------------------------------------------------------
__launch_bounds__(1024, 4)
__global__ void k_attn6(const float* __restrict__ qslab, const float* __restrict__ kslab,
                        const float* __restrict__ vslab, const float* __restrict__ mask,
                        const float* __restrict__ bmg, const int* __restrict__ relidx,
                        const float* __restrict__ plw, const float* __restrict__ pww,
                        const float* __restrict__ pwb, float* __restrict__ xout) {
  __shared__ __align__(16) ushort_t SA[2416 * 16];       // 77,312 B
  __shared__ __align__(16) ushort_t PP[NH * TOK * 56];   // 65,856 B
  __shared__ float bm_s[169 * 16];                       // 10,816 B
  __shared__ ushort_t ridx_s[2416];                      //  4,832 B

  const int tid = threadIdx.x;
  const int b = blockIdx.x;
  const size_t base = (size_t)b * TOK * CDIM;
  const int l = tid & 63, l15 = l & 15, l16 = l >> 4;
  const int wv = tid >> 6;                // 0..15
  const int rt = wv >> 2;                 // n-tile (A & E)
  const int ct = wv & 3;                  // m-tile (A)
  const float SCL = 0.17677669529663687f * L2E;

  // ---- preamble: aux preload + zero S h-slots 12..15 + zero tail rows fully
  for (int i = tid; i < 169 * 16; i += 1024) bm_s[i] = bmg[i];
  for (int i = tid; i < 2416; i += 1024) ridx_s[i] = (i < NPT) ? (ushort_t)relidx[i] : 0;
  for (int p = tid; p < 2416; p += 1024) *(uint2*)&SA[p * 16 + 12] = uint2{0u, 0u};
  if (tid < (2416 - NPT) * 4) *(uint2*)&SA[NPT * 16 + tid * 4] = uint2{0u, 0u};

  // ---- Phase A: S[p][h] = raw q.k, h-quad batched b64 writes
  {
    const int nrow = rt * 16 + l15;
    const int mrow = ct * 16 + l15;
#pragma unroll
    for (int hq = 0; hq < 3; ++hq) {
      f32x4 sacc[4];
#pragma unroll
      for (int hh = 0; hh < 4; ++hh) {
        int h = hq * 4 + hh;
        bf16x8 af = {0,0,0,0,0,0,0,0}, bf = {0,0,0,0,0,0,0,0};
        if (nrow < TOK) {
          const float4* qp = (const float4*)(qslab + base + (size_t)nrow * CDIM + h * HDIM + l16 * 8);
          af = pack8(qp[0], qp[1]);
        }
        if (mrow < TOK) {
          const float4* kp = (const float4*)(kslab + base + (size_t)mrow * CDIM + h * HDIM + l16 * 8);
          bf = pack8(kp[0], kp[1]);
        }
        f32x4 z = {0.f, 0.f, 0.f, 0.f};
        sacc[hh] = __builtin_amdgcn_mfma_f32_16x16x32_bf16(af, bf, z, 0, 0, 0);
      }
#pragma unroll
      for (int j = 0; j < 4; ++j) {
        int nj = rt * 16 + l16 * 4 + j;
        if (nj < TOK && mrow < TOK) {
          uint2 w;
          w.x = pk2(sacc[0][j], sacc[1][j]);
          w.y = pk2(sacc[2][j], sacc[3][j]);
          *(uint2*)&SA[(nj * TOK + mrow) * 16 + hq * 4] = w;
        }
      }
    }
  }
  __syncthreads();   // b1

  // ---- per-wave-row: mix1 + softmax + mix2
  {
    const float* maskw = mask + (size_t)(b & (NWIN - 1)) * NPT;
    float apf[8], bpf[8];
#pragma unroll
    for (int j = 0; j < 8; ++j) {
      int kj = l16 * 8 + j;
      apf[j] = (l15 < NH && kj < NH) ? plw[l15 * NH + kj] * SCL : 0.f;
      bpf[j] = (l15 < NH && kj < NH) ? pww[l15 * NH + kj] : 0.f;
    }
    const bf16x8 aplw = pack8f(apf);
    const bf16x8 bpww = pack8f(bpf);
    const float pwbv = (l15 < NH) ? pwb[l15] : 0.f;

    for (int n = wv; n < TOK; n += 16) {
      const int pb0 = n * TOK;
      float ev[4][4];                  // [mc][j]
      float rs[4] = {0.f, 0.f, 0.f, 0.f};
#pragma unroll
      for (int mc = 0; mc < 4; ++mc) {
        int m = mc * 16 + l15;
        int p = pb0 + m;
        int pc = (p < NPT) ? p : (NPT - 1);
        bf16x8 sf = {0,0,0,0,0,0,0,0};                 // K-slots 16..31 MUST be 0
        if (l16 < 2) sf = *(const bf16x8*)&SA[p * 16 + l16 * 8];
        int rid = (int)ridx_s[pc];
        float4 bm4 = *(const float4*)&bm_s[rid * 16 + l16 * 4];
        float mk = maskw[pc] * L2E;
        f32x4 cini = {bm4.x + mk, bm4.y + mk, bm4.z + mk, bm4.w + mk};
        f32x4 o = __builtin_amdgcn_mfma_f32_16x16x32_bf16(aplw, sf, cini, 0, 0, 0);
        bool mv = (m < TOK);
#pragma unroll
        for (int j = 0; j < 4; ++j) {
          int g = l16 * 4 + j;
          float e = (mv && g < NH) ? exp2f(o[j]) : 0.f;
          ev[mc][j] = e;
          rs[j] += e;
        }
      }
      // butterfly sum over the 16 m-lanes (lane bits 0..3)
#pragma unroll
      for (int d = 1; d < 16; d <<= 1) {
#pragma unroll
        for (int j = 0; j < 4; ++j) rs[j] += __shfl_xor(rs[j], d, 64);
      }
      float inv[4];
#pragma unroll
      for (int j = 0; j < 4; ++j) inv[j] = (rs[j] > 0.f) ? 1.f / rs[j] : 0.f;

      // P in-place over S (own rows only, m<49): b64
#pragma unroll
      for (int mc = 0; mc < 4; ++mc) {
        int m = mc * 16 + l15;
        if (m < TOK) {
          uint2 w;
          w.x = pk2(ev[mc][0] * inv[0], ev[mc][1] * inv[1]);
          w.y = pk2(ev[mc][2] * inv[2], ev[mc][3] * inv[3]);
          *(uint2*)&SA[(pb0 + m) * 16 + l16 * 4] = w;
        }
      }
      // mix2 unswapped: rows=m-quad, cols=g'; b128 read (K-guarded), b64 write
#pragma unroll
      for (int mc = 0; mc < 4; ++mc) {
        bf16x8 pf8 = {0,0,0,0,0,0,0,0};                // K-slots 16..31 MUST be 0
        if (l16 < 2) pf8 = *(const bf16x8*)&SA[(pb0 + mc * 16 + l15) * 16 + l16 * 8];
        f32x4 cd = {pwbv, pwbv, pwbv, pwbv};
        f32x4 o = __builtin_amdgcn_mfma_f32_16x16x32_bf16(pf8, bpww, cd, 0, 0, 0);
        int m0 = mc * 16 + l16 * 4;
        if (l15 < NH && m0 < 56) {
          float z0 = (m0     < TOK) ? o[0] : 0.f;
          float z1 = (m0 + 1 < TOK) ? o[1] : 0.f;
          float z2 = (m0 + 2 < TOK) ? o[2] : 0.f;
          float z3 = (m0 + 3 < TOK) ? o[3] : 0.f;
          uint2 w;
          w.x = pk2(z0, z1);
          w.y = pk2(z2, z3);
          *(uint2*)&PP[l15 * 2744 + n * 56 + m0] = w;
        }
      }
    }
  }
  __syncthreads();   // b2

  // ---- Vst staging into SA region: Vst[c][m64], zero m>=49
  ushort_t* Vst = SA;
  for (int i = tid; i < CDIM * 16; i += 1024) {
    int mq = i / CDIM, c = i - mq * CDIM;
    float f0 = 0.f, f1 = 0.f, f2 = 0.f, f3 = 0.f;
    int m = mq * 4;
    if (m     < TOK) f0 = vslab[base + (size_t)(m    ) * CDIM + c];
    if (m + 1 < TOK) f1 = vslab[base + (size_t)(m + 1) * CDIM + c];
    if (m + 2 < TOK) f2 = vslab[base + (size_t)(m + 2) * CDIM + c];
    if (m + 3 < TOK) f3 = vslab[base + (size_t)(m + 3) * CDIM + c];
    uint2 u;
    u.x = pk2(f0, f1);
    u.y = pk2(f2, f3);
    *(uint2*)&Vst[c * 72 + mq * 4] = u;
  }
  __syncthreads();   // b3

  // ---- Phase E: PV via MFMA; wave=(rt, dt, gh) -> 6 heads each
  {
    const int dt = (wv >> 1) & 1;
    const int gh = wv & 1;
#pragma unroll 2
    for (int gi = 0; gi < 6; ++gi) {
      int g = gh * 6 + gi;
      f32x4 acc = {0.f, 0.f, 0.f, 0.f};
#pragma unroll
      for (int ks = 0; ks < 2; ++ks) {
        bf16x8 pa8 = {0,0,0,0,0,0,0,0};
        if (!(ks == 1 && l16 == 3))    // k-slots 56..63 are virtual pad: must be 0
          pa8 = *(const bf16x8*)&PP[g * 2744 + (rt * 16 + l15) * 56 + ks * 32 + l16 * 8];
        bf16x8 vb8 = *(const bf16x8*)&Vst[(g * HDIM + dt * 16 + l15) * 72 + ks * 32 + l16 * 8];
        acc = __builtin_amdgcn_mfma_f32_16x16x32_bf16(pa8, vb8, acc, 0, 0, 0);
      }
#pragma unroll
      for (int j = 0; j < 4; ++j) {
        int n = rt * 16 + l16 * 4 + j;
        if (n < TOK)
          xout[base + (size_t)n * CDIM + g * HDIM + dt * 16 + l15] = acc[j];
      }
    }
  }
}

// ---------------------------------------------------------------------------
// Kernel 3: output projection, bf16 MFMA, in-place (unchanged; verified).
// ---------------------------------------------------------------------------
__launch_bounds__(512)
__global__ void k_proj_mfma(float* __restrict__ Y, const float* __restrict__ W,
                            const float* __restrict__ Bv) {
  __shared__ ushort_t Asb[128 * 392];
  __shared__ ushort_t Bsb[384 * 40];
  const int tid = threadIdx.x;
  const int l = tid & 63;
  const int wv = tid >> 6;
  const int wr = wv >> 2, wc = wv & 3;
  const int row0 = blockIdx.x * 128;

#pragma unroll
  for (int i = 0; i < 12; ++i) {
    int cid = tid + i * 512;
    int r = cid / 48, c8 = cid % 48;
    const float4* s = (const float4*)&Y[(size_t)(row0 + r) * CDIM + c8 * 8];
    float4 a = s[0], b = s[1];
    uint4 o;
    o.x = (uint32)f2bf(a.x) | ((uint32)f2bf(a.y) << 16);
    o.y = (uint32)f2bf(a.z) | ((uint32)f2bf(a.w) << 16);
    o.z = (uint32)f2bf(b.x) | ((uint32)f2bf(b.y) << 16);
    o.w = (uint32)f2bf(b.z) | ((uint32)f2bf(b.w) << 16);
    *(uint4*)&Asb[r * 392 + c8 * 8] = o;
  }

  f32x4 acc[4][6];
#pragma unroll
  for (int i = 0; i < 4; ++i)
#pragma unroll
    for (int j = 0; j < 6; ++j)
#pragma unroll
      for (int e = 0; e < 4; ++e) acc[i][j][e] = 0.f;

  for (int kb = 0; kb < CDIM; kb += 32) {
    __syncthreads();
#pragma unroll
    for (int i = 0; i < 3; ++i) {
      int cid = tid + i * 512;
      int col = cid >> 2, k8 = cid & 3;
      const float4* s = (const float4*)&W[(size_t)col * CDIM + kb + k8 * 8];
      float4 a = s[0], b = s[1];
      uint4 o;
      o.x = (uint32)f2bf(a.x) | ((uint32)f2bf(a.y) << 16);
      o.y = (uint32)f2bf(a.z) | ((uint32)f2bf(a.w) << 16);
      o.z = (uint32)f2bf(b.x) | ((uint32)f2bf(b.y) << 16);
      o.w = (uint32)f2bf(b.z) | ((uint32)f2bf(b.w) << 16);
      *(uint4*)&Bsb[col * 40 + k8 * 8] = o;
    }
    __syncthreads();
    bf16x8 af[4], bfr[6];
#pragma unroll
    for (int mt = 0; mt < 4; ++mt)
      af[mt] = *(const bf16x8*)&Asb[(wr * 64 + mt * 16 + (l & 15)) * 392 + kb + (l >> 4) * 8];
#pragma unroll
    for (int nt = 0; nt < 6; ++nt)
      bfr[nt] = *(const bf16x8*)&Bsb[(wc * 96 + nt * 16 + (l & 15)) * 40 + (l >> 4) * 8];
#pragma unroll
    for (int mt = 0; mt < 4; ++mt)
#pragma unroll
      for (int nt = 0; nt < 6; ++nt)
        acc[mt][nt] = __builtin_amdgcn_mfma_f32_16x16x32_bf16(af[mt], bfr[nt], acc[mt][nt], 0, 0, 0);
  }

#pragma unroll
  for (int nt = 0; nt < 6; ++nt) {
    int col = wc * 96 + nt * 16 + (l & 15);
    float bv = Bv[col];
#pragma unroll
    for (int mt = 0; mt < 4; ++mt) {
      int rbase = row0 + wr * 64 + mt * 16 + (l >> 4) * 4;
#pragma unroll
      for (int j = 0; j < 4; ++j)
        Y[(size_t)(rbase + j) * CDIM + col] = acc[mt][nt][j] + bv;
    }
  }
}

// ---------------------------------------------------------------------------
extern "C" void kernel_launch(void* const* d_in, const int* in_sizes, int n_in,
                              void* d_out, int out_size, void* d_ws, size_t ws_size,
                              hipStream_t stream) {
  const float* x      = (const float*)d_in[0];
  const float* mask   = (const float*)d_in[1];
  const float* qkv_w  = (const float*)d_in[2];
  const float* qkv_b  = (const float*)d_in[3];
  const float* rpb    = (const float*)d_in[4];
  const float* plw    = (const float*)d_in[5];
  const float* plb    = (const float*)d_in[6];
  const float* pww    = (const float*)d_in[7];
  const float* pwb    = (const float*)d_in[8];
  const float* projw  = (const float*)d_in[9];
  const float* projb  = (const float*)d_in[10];
  const int*   relidx = (const int*)d_in[11];

  float* out   = (float*)d_out;
  float* qslab = out + (size_t)OUTSZ;
  float* kslab = out + 2 * (size_t)OUTSZ;
  float* vslab = out + 3 * (size_t)OUTSZ;

  ushort_t* Xb = (ushort_t*)out;                    // bf16 scratch in out slab
  ushort_t* Wb = (ushort_t*)(out + 70000000);
  float*    bm = (float*)d_ws;                      // 169*16 f32 biasmix

  k_cvt<<<(OUTSZ / 8 + 255) / 256, 256, 0, stream>>>(x, Xb, OUTSZ / 8);
  k_cvt<<<(3 * CDIM * CDIM / 8 + 255) / 256, 256, 0, stream>>>(qkv_w, Wb, 3 * CDIM * CDIM / 8);
  k_bias<<<(169 * 16 + 255) / 256, 256, 0, stream>>>(rpb, plw, plb, bm);

  dim3 g1(BTOT * TOK / 128, (3 * CDIM) / 128);
  k_qkv_mfma<<<g1, 256, 0, stream>>>(Xb, Wb, qkv_b, qslab);

  k_attn6<<<BTOT, 1024, 0, stream>>>(qslab, kslab, vslab, mask, bm, relidx,
                                     plw, pww, pwb, out);

  k_proj_mfma<<<BTOT * TOK / 128, 512, 0, stream>>>(out, projw, projb);
}